// Round 1
// 643.564 us; speedup vs baseline: 1.1891x; 1.1891x over previous
//
#include <hip/hip_runtime.h>
#include <math.h>

// Problem constants
#define BATCH 2
#define C3 256
#define C2 128
#define C1 64
#define HH 48
#define WW 48
#define L 2304          // 48*48 unfold positions
#define GK 256          // channel dim for G-GEMM
#define BK2 64          // K-tile (bf16) for G-GEMM
#define NSEG 16
#define SEG 144         // 2304/16

// Output flat offsets (float elements)
#define OFF_T3 13824
#define OFF_T2 3552768
#define OFF_T1 10630656

typedef __bf16 bf16x8 __attribute__((ext_vector_type(8)));
typedef float  f32x4  __attribute__((ext_vector_type(4)));
typedef float  f32x2  __attribute__((ext_vector_type(2)));

__device__ __forceinline__ void gload16(const void* g, void* l) {
    __builtin_amdgcn_global_load_lds(
        (const __attribute__((address_space(1))) void*)g,
        (__attribute__((address_space(3))) void*)l, 16, 0, 0);
}

__device__ __forceinline__ void nts4(float* p, float a, float b, float c, float d) {
    f32x4 v = {a, b, c, d};
    __builtin_nontemporal_store(v, (f32x4*)p);
}
__device__ __forceinline__ void nts2(float* p, float a, float b) {
    f32x2 v = {a, b};
    __builtin_nontemporal_store(v, (f32x2*)p);
}

// ---------------- per-pixel channel sum of squares (both images) ----------------
__global__ void ssq_kernel(const float* __restrict__ lr, const float* __restrict__ refsr,
                           float* __restrict__ ssQ, float* __restrict__ ssK) {
    int idx = blockIdx.x * 256 + threadIdx.x;
    if (idx >= BATCH * L) return;
    const float* img = blockIdx.y ? refsr : lr;
    float* ss = blockIdx.y ? ssK : ssQ;
    int b = idx / L, yx = idx % L;
    const float* p = img + (size_t)b * C3 * L + yx;
    float s = 0.f;
    #pragma unroll 4
    for (int c = 0; c < C3; ++c) { float v = p[(size_t)c * L]; s += v * v; }
    ss[idx] = s;
}

// ---------------- 3x3 window sum -> 1/max(sqrt, eps) (both) ----------------
__global__ void norm_kernel(const float* __restrict__ ssQ, const float* __restrict__ ssK,
                            float* __restrict__ rnQ, float* __restrict__ rnK) {
    int idx = blockIdx.x * 256 + threadIdx.x;
    if (idx >= BATCH * L) return;
    const float* ss = blockIdx.y ? ssK : ssQ;
    float* rn = blockIdx.y ? rnK : rnQ;
    int b = idx / L, l = idx % L;
    int ly = l / WW, lx = l % WW;
    const float* s = ss + b * L;
    float acc = 0.f;
    #pragma unroll
    for (int dy = -1; dy <= 1; ++dy) {
        int yy = ly + dy;
        if ((unsigned)yy >= (unsigned)HH) continue;
        #pragma unroll
        for (int dx = -1; dx <= 1; ++dx) {
            int xx = lx + dx;
            if ((unsigned)xx >= (unsigned)WW) continue;
            acc += s[yy * WW + xx];
        }
    }
    float n = sqrtf(acc);
    n = fmaxf(n, 1e-12f);
    rn[idx] = 1.0f / n;
}

// ---------------- transpose [C][pix] -> [pix][C] + bf16 hi/lo split (both images) ----
// grid: (36 u-tiles, 4 c-tiles, B*2); 64x64 fp32 tile via LDS.
__global__ __launch_bounds__(256) void split_t(const float* __restrict__ lr,
                                               const float* __restrict__ refsr,
                                               __bf16* __restrict__ Qhi, __bf16* __restrict__ Qlo,
                                               __bf16* __restrict__ Khi, __bf16* __restrict__ Klo) {
    __shared__ float tile[64][65];
    int bz = blockIdx.z;
    int b = bz >> 1;
    const float* img = (bz & 1) ? refsr : lr;
    __bf16* dh = (bz & 1) ? Khi : Qhi;
    __bf16* dl = (bz & 1) ? Klo : Qlo;
    int u0 = blockIdx.x * 64, c0 = blockIdx.y * 64;
    int t = threadIdx.x;
    {
        int ul = t & 63, cl0 = t >> 6;
        const float* src = img + ((size_t)b * C3 + c0) * L + u0;
        #pragma unroll
        for (int r = 0; r < 16; ++r) {
            int cl = cl0 + r * 4;
            tile[cl][ul] = src[(size_t)cl * L + ul];
        }
    }
    __syncthreads();
    {
        int cl = t & 63, ul0 = t >> 6;
        __bf16* oh = dh + ((size_t)b * L + u0) * GK + c0 + cl;
        __bf16* ol = dl + ((size_t)b * L + u0) * GK + c0 + cl;
        #pragma unroll
        for (int r = 0; r < 16; ++r) {
            int ul = ul0 + r * 4;
            float v = tile[cl][ul];
            __bf16 h = (__bf16)v;
            float lo = v - (float)h;
            oh[(size_t)ul * GK] = h;
            ol[(size_t)ul * GK] = (__bf16)lo;
        }
    }
}

// ---------------- split-bf16 MFMA GEMM NT over K=256: G[u,v] ----------------
// 64(u) x 128(v) tiles, BK=64. LDS XOR-swizzle (slot ^= row&7) applied on BOTH
// the global source address (gload_lds writes linearly) and the ds_read slot
// -> conflict-free fragment reads (was 8-way at 64B rows).
__global__ __launch_bounds__(256) void gemm_g(const __bf16* __restrict__ Khi,
                                              const __bf16* __restrict__ Klo,
                                              const __bf16* __restrict__ Qhi,
                                              const __bf16* __restrict__ Qlo,
                                              float* __restrict__ Gg) {
    __shared__ __align__(16) __bf16 Ah[64 * BK2];
    __shared__ __align__(16) __bf16 Al[64 * BK2];
    __shared__ __align__(16) __bf16 Bh[128 * BK2];
    __shared__ __align__(16) __bf16 Bl[128 * BK2];
    int t = threadIdx.x;
    int lane = t & 63;
    int wv = t >> 6;
    int b = blockIdx.z;
    size_t ioff = (size_t)b * L * GK;
    const __bf16* Ahg = Khi + ioff;   // rows u (refsr)
    const __bf16* Alg = Klo + ioff;
    const __bf16* Bhg = Qhi + ioff;   // rows v (lr)
    const __bf16* Blg = Qlo + ioff;
    int m0 = blockIdx.x * 128;
    int l0 = blockIdx.y * 64;
    int wl = wv >> 1, wm = wv & 1;    // wave tile: 32(u) x 64(v)
    int q = lane >> 4, r16 = lane & 15;

    f32x4 acc[2][4];
    #pragma unroll
    for (int i = 0; i < 2; i++)
        #pragma unroll
        for (int j = 0; j < 4; j++) acc[i][j] = (f32x4)(0.f);

    for (int k0 = 0; k0 < GK; k0 += BK2) {
        #pragma unroll
        for (int hh = 0; hh < 2; ++hh) {          // A: 512 chunks of 16B
            int c = t + hh * 256;
            int row = c >> 3, qo = c & 7;
            size_t ga = (size_t)(l0 + row) * GK + k0 + ((qo ^ (row & 7)) * 8);
            gload16(Ahg + ga, &Ah[c * 8]);
            gload16(Alg + ga, &Al[c * 8]);
        }
        #pragma unroll
        for (int hh = 0; hh < 4; ++hh) {          // B: 1024 chunks
            int c = t + hh * 256;
            int row = c >> 3, qo = c & 7;
            size_t gb = (size_t)(m0 + row) * GK + k0 + ((qo ^ (row & 7)) * 8);
            gload16(Bhg + gb, &Bh[c * 8]);
            gload16(Blg + gb, &Bl[c * 8]);
        }
        __syncthreads();

        #pragma unroll
        for (int h = 0; h < 2; ++h) {             // two k-32 halves of BK=64
            bf16x8 ah[2], al[2], bh[4], bl[4];
            #pragma unroll
            for (int i = 0; i < 2; ++i) {
                int row = wl * 32 + i * 16 + r16;
                int ch = (h * 4 + q) ^ (row & 7);
                ah[i] = *(const bf16x8*)&Ah[row * BK2 + ch * 8];
                al[i] = *(const bf16x8*)&Al[row * BK2 + ch * 8];
            }
            #pragma unroll
            for (int j = 0; j < 4; ++j) {
                int row = wm * 64 + j * 16 + r16;
                int ch = (h * 4 + q) ^ (row & 7);
                bh[j] = *(const bf16x8*)&Bh[row * BK2 + ch * 8];
                bl[j] = *(const bf16x8*)&Bl[row * BK2 + ch * 8];
            }
            #pragma unroll
            for (int i = 0; i < 2; ++i)
                #pragma unroll
                for (int j = 0; j < 4; ++j) {
                    acc[i][j] = __builtin_amdgcn_mfma_f32_16x16x32_bf16(ah[i], bh[j], acc[i][j], 0, 0, 0);
                    acc[i][j] = __builtin_amdgcn_mfma_f32_16x16x32_bf16(ah[i], bl[j], acc[i][j], 0, 0, 0);
                    acc[i][j] = __builtin_amdgcn_mfma_f32_16x16x32_bf16(al[i], bh[j], acc[i][j], 0, 0, 0);
                }
        }
        __syncthreads();
    }

    float* Cb = Gg + (size_t)b * L * L;
    #pragma unroll
    for (int i = 0; i < 2; ++i) {
        int rowb = l0 + wl * 32 + i * 16 + q * 4;
        #pragma unroll
        for (int j = 0; j < 4; ++j) {
            int col = m0 + wm * 64 + j * 16 + r16;
            #pragma unroll
            for (int r = 0; r < 4; ++r)
                __builtin_nontemporal_store(acc[i][j][r], Cb + (size_t)(rowb + r) * L + col);
        }
    }
}

// ---------------- R[l,m] = rnK[l]*rnQ[m]*sum_{9 diag shifts} G[l+s, m+s] ----------------
// grid: (576, BATCH), block 576. Each block: 4 rows l, each thread 4 cols m.
__global__ __launch_bounds__(576) void stencil_R(const float* __restrict__ G,
                                                 const float* __restrict__ rnK,
                                                 const float* __restrict__ rnQ,
                                                 float* __restrict__ R) {
    int b = blockIdx.y;
    int lbase = blockIdx.x * 4;
    int m0 = threadIdx.x * 4;
    const float* Gb = G + (size_t)b * L * L;
    int mdiv[4], mmod[4];
    #pragma unroll
    for (int j = 0; j < 4; ++j) { int m = m0 + j; mdiv[j] = m / 48; mmod[j] = m % 48; }
    const float* rq = rnQ + b * L + m0;
    float rqv[4] = { rq[0], rq[1], rq[2], rq[3] };

    #pragma unroll
    for (int li = 0; li < 4; ++li) {
        int l = lbase + li;
        int ly = l / 48, lx = l % 48;
        float acc[4] = {0.f, 0.f, 0.f, 0.f};
        #pragma unroll
        for (int dy = -1; dy <= 1; ++dy) {
            int lyy = ly + dy;
            if ((unsigned)lyy >= 48u) continue;
            #pragma unroll
            for (int dx = -1; dx <= 1; ++dx) {
                int lxx = lx + dx;
                if ((unsigned)lxx >= 48u) continue;
                int s = dy * 48 + dx;
                const float* Grow = Gb + (size_t)(l + s) * L + s + m0;
                #pragma unroll
                for (int j = 0; j < 4; ++j) {
                    if ((unsigned)(mdiv[j] + dy) < 48u && (unsigned)(mmod[j] + dx) < 48u)
                        acc[j] += Grow[j];
                }
            }
        }
        float rk = rnK[b * L + l];
        float* out = R + (size_t)b * L * L + (size_t)l * L + m0;
        nts4(out, acc[0] * rk * rqv[0], acc[1] * rk * rqv[1],
                  acc[2] * rk * rqv[2], acc[3] * rk * rqv[3]);
    }
}

// ---------------- segmented argmax over l (ties -> lowest l) ----------------
__global__ void argmax_part(const float* __restrict__ R, float* __restrict__ pv, int* __restrict__ pi) {
    int m = blockIdx.x * 256 + threadIdx.x;
    int seg = blockIdx.y, b = blockIdx.z;
    const float* Rb = R + (size_t)b * L * L;
    float bv = -3.4e38f; int bi = 0;
    int l0 = seg * SEG;
    #pragma unroll 4
    for (int j = 0; j < SEG; j++) {
        float v = Rb[(size_t)(l0 + j) * L + m];
        if (v > bv) { bv = v; bi = l0 + j; }
    }
    int o = (b * NSEG + seg) * L + m;
    pv[o] = bv; pi[o] = bi;
}

__global__ void argmax_merge(const float* __restrict__ pv, const int* __restrict__ pi,
                             int* __restrict__ hidx) {
    int m = blockIdx.x * 256 + threadIdx.x;
    int b = blockIdx.y;
    float bv = -3.4e38f; int bi = 0;
    #pragma unroll
    for (int s = 0; s < NSEG; s++) {
        int o = (b * NSEG + s) * L + m;
        float v = pv[o];
        if (v > bv) { bv = v; bi = pi[o]; }
    }
    hidx[b * L + m] = bi;
}

// ---------------- segmented top-3 of s_l = R[hidx[l], m] ----------------
__global__ void top3_part(const float* __restrict__ R, const int* __restrict__ hidx,
                          float* __restrict__ pv, int* __restrict__ pr) {
    int m = blockIdx.x * 256 + threadIdx.x;
    int seg = blockIdx.y, b = blockIdx.z;
    const float* Rb = R + (size_t)b * L * L;
    __shared__ int hrow_s[SEG];
    if (threadIdx.x < SEG) hrow_s[threadIdx.x] = hidx[b * L + seg * SEG + threadIdx.x];
    __syncthreads();
    float v0 = -3.4e38f, v1 = -3.4e38f, v2 = -3.4e38f;
    int r0 = 0, r1 = 0, r2 = 0;
    #pragma unroll 4
    for (int j = 0; j < SEG; j++) {
        int row = hrow_s[j];
        float v = Rb[(size_t)row * L + m];
        if (v > v0)      { v2 = v1; r2 = r1; v1 = v0; r1 = r0; v0 = v; r0 = row; }
        else if (v > v1) { v2 = v1; r2 = r1; v1 = v;  r1 = row; }
        else if (v > v2) { v2 = v;  r2 = row; }
    }
    size_t o = ((size_t)(b * NSEG + seg) * 3) * L + m;
    pv[o] = v0; pv[o + L] = v1; pv[o + 2 * L] = v2;
    pr[o] = r0; pr[o + L] = r1; pr[o + 2 * L] = r2;
}

__global__ void top3_merge(const float* __restrict__ pv, const int* __restrict__ pr,
                           float* __restrict__ outS, int* __restrict__ effp) {
    int m = blockIdx.x * 256 + threadIdx.x;
    int b = blockIdx.y;
    float v0 = -3.4e38f, v1 = -3.4e38f, v2 = -3.4e38f;
    int r0 = 0, r1 = 0, r2 = 0;
    for (int s = 0; s < NSEG; s++) {
        size_t o = ((size_t)(b * NSEG + s) * 3) * L + m;
        #pragma unroll
        for (int j = 0; j < 3; j++) {
            float v = pv[o + (size_t)j * L];
            int r = pr[o + (size_t)j * L];
            if (v > v0)      { v2 = v1; r2 = r1; v1 = v0; r1 = r0; v0 = v; r0 = r; }
            else if (v > v1) { v2 = v1; r2 = r1; v1 = v;  r1 = r; }
            else if (v > v2) { v2 = v;  r2 = r; }
        }
    }
    outS[(0 * BATCH + b) * L + m] = v0;
    outS[(1 * BATCH + b) * L + m] = v1;
    outS[(2 * BATCH + b) * L + m] = v2;
    effp[(b * 3 + 0) * L + m] = ((r0 / 48) << 8) | (r0 % 48);
    effp[(b * 3 + 1) * L + m] = ((r1 / 48) << 8) | (r1 % 48);
    effp[(b * 3 + 2) * L + m] = ((r2 / 48) << 8) | (r2 % 48);
}

// ---------------- folds, XCD-swizzled so one (b,c) plane stays on one XCD's L2 ----------
__global__ __launch_bounds__(256) void fold_t1(const float* __restrict__ ref, const int* __restrict__ effp,
                                               float* __restrict__ outT) {
    const int W = 192;
    int blk = blockIdx.x;
    int xcd = blk & 7;
    int r = blk >> 3;
    int tile = r % 36;
    int rr = r / 36;
    int i = rr % 3;
    int pw = rr / 3;                  // 0..15
    int plane = xcd + 8 * pw;         // 0..127
    int b = plane >> 6, c = plane & 63;
    int id = tile * 256 + threadIdx.x;     // y*48 + qx in [0, 9216)
    int y = id / 48, qx = id % 48;
    int qy = y >> 2, ry = y & 3;
    const int* e = effp + (b * 3 + i) * L;
    const float* src = ref + ((size_t)b * C1 + c) * (W * W);
    float4 s = make_float4(0.f, 0.f, 0.f, 0.f);
    #pragma unroll
    for (int dh = -1; dh <= 1; ++dh) {
        int ho = qy + dh;
        if ((unsigned)ho >= 48u) continue;
        #pragma unroll
        for (int dw = -1; dw <= 1; ++dw) {
            int wo = qx + dw;
            if ((unsigned)wo >= 48u) continue;
            int ep = e[ho * 48 + wo];
            int yq = (ep >> 8) - dh, xq = (ep & 255) - dw;
            if ((unsigned)yq >= 48u || (unsigned)xq >= 48u) continue;
            const float4 v = *(const float4*)(src + (yq * 4 + ry) * W + xq * 4);
            s.x += v.x; s.y += v.y; s.z += v.z; s.w += v.w;
        }
    }
    const float k = 1.0f / 9.0f;
    nts4(outT + (((size_t)i * BATCH + b) * C1 + c) * (size_t)(W * W) + y * W + qx * 4,
         s.x * k, s.y * k, s.z * k, s.w * k);
}

__global__ __launch_bounds__(256) void fold_t2(const float* __restrict__ ref, const int* __restrict__ effp,
                                               float* __restrict__ outT) {
    const int W = 96;
    int blk = blockIdx.x;
    int xcd = blk & 7;
    int r = blk >> 3;
    int tile = r % 18;
    int rr = r / 18;
    int i = rr % 3;
    int pw = rr / 3;                  // 0..31
    int plane = xcd + 8 * pw;         // 0..255
    int b = plane >> 7, c = plane & 127;
    int id = tile * 256 + threadIdx.x;     // y*48 + qx in [0, 4608)
    int y = id / 48, qx = id % 48;
    int qy = y >> 1, ry = y & 1;
    const int* e = effp + (b * 3 + i) * L;
    const float* src = ref + ((size_t)b * C2 + c) * (W * W);
    float2 s = make_float2(0.f, 0.f);
    #pragma unroll
    for (int dh = -1; dh <= 1; ++dh) {
        int ho = qy + dh;
        if ((unsigned)ho >= 48u) continue;
        #pragma unroll
        for (int dw = -1; dw <= 1; ++dw) {
            int wo = qx + dw;
            if ((unsigned)wo >= 48u) continue;
            int ep = e[ho * 48 + wo];
            int yq = (ep >> 8) - dh, xq = (ep & 255) - dw;
            if ((unsigned)yq >= 48u || (unsigned)xq >= 48u) continue;
            const float2 v = *(const float2*)(src + (yq * 2 + ry) * W + xq * 2);
            s.x += v.x; s.y += v.y;
        }
    }
    const float k = 1.0f / 9.0f;
    nts2(outT + (((size_t)i * BATCH + b) * C2 + c) * (size_t)(W * W) + y * W + qx * 2,
         s.x * k, s.y * k);
}

__global__ __launch_bounds__(192) void fold_t3(const float* __restrict__ ref, const int* __restrict__ effp,
                                               float* __restrict__ outT) {
    const int W = 48;
    int blk = blockIdx.x;
    int xcd = blk & 7;
    int r = blk >> 3;
    int tile = r % 3;
    int rr = r / 3;
    int i = rr % 3;
    int pw = rr / 3;                  // 0..63
    int plane = xcd + 8 * pw;         // 0..511
    int b = plane >> 8, c = plane & 255;
    int id = tile * 192 + threadIdx.x;     // y*12 + xq in [0, 576)
    int y = id / 12, x0 = (id % 12) * 4;
    const int* e = effp + (b * 3 + i) * L;
    const float* src = ref + ((size_t)b * C3 + c) * (W * W);
    float s[4] = {0.f, 0.f, 0.f, 0.f};
    #pragma unroll
    for (int dh = -1; dh <= 1; ++dh) {
        int ho = y + dh;
        if ((unsigned)ho >= 48u) continue;
        int ep6[6];
        #pragma unroll
        for (int j = 0; j < 6; ++j) {
            int wo = x0 - 1 + j;
            ep6[j] = ((unsigned)wo < 48u) ? e[ho * 48 + wo] : -1;
        }
        #pragma unroll
        for (int xi = 0; xi < 4; ++xi) {
            #pragma unroll
            for (int dw = -1; dw <= 1; ++dw) {
                int ep = ep6[xi + dw + 1];
                if (ep < 0) continue;
                int yy = (ep >> 8) - dh, xx = (ep & 255) - dw;
                if ((unsigned)yy >= 48u || (unsigned)xx >= 48u) continue;
                s[xi] += src[yy * W + xx];
            }
        }
    }
    const float k = 1.0f / 9.0f;
    nts4(outT + (((size_t)i * BATCH + b) * C3 + c) * (size_t)(W * W) + y * W + x0,
         s[0] * k, s[1] * k, s[2] * k, s[3] * k);
}

extern "C" void kernel_launch(void* const* d_in, const int* in_sizes, int n_in,
                              void* d_out, int out_size, void* d_ws, size_t ws_size,
                              hipStream_t stream) {
    const float* lr    = (const float*)d_in[0];
    const float* refsr = (const float*)d_in[1];
    const float* ref1  = (const float*)d_in[2];
    const float* ref2  = (const float*)d_in[3];
    const float* ref3  = (const float*)d_in[4];
    float* out = (float*)d_out;

    float*  R   = (float*)d_ws;                              // B*L*L fp32
    float*  G   = R + (size_t)BATCH * L * L;                 // B*L*L fp32
    __bf16* Khi = (__bf16*)(G + (size_t)BATCH * L * L);      // B*L*GK bf16 each
    __bf16* Klo = Khi + (size_t)BATCH * L * GK;
    __bf16* Qhi = Klo + (size_t)BATCH * L * GK;
    __bf16* Qlo = Qhi + (size_t)BATCH * L * GK;
    float* ssQ = (float*)(Qlo + (size_t)BATCH * L * GK);
    float* ssK = ssQ + BATCH * L;
    float* rnQ = ssK + BATCH * L;
    float* rnK = rnQ + BATCH * L;
    float* apv = rnK + BATCH * L;
    float* pv  = apv + BATCH * NSEG * L;
    int*   api = (int*)(pv + (size_t)BATCH * NSEG * 3 * L);
    int*   pr  = api + BATCH * NSEG * L;
    int*   hidx = pr + (size_t)BATCH * NSEG * 3 * L;
    int*   effp = hidx + BATCH * L;

    ssq_kernel<<<dim3(18, 2), 256, 0, stream>>>(lr, refsr, ssQ, ssK);
    norm_kernel<<<dim3(18, 2), 256, 0, stream>>>(ssQ, ssK, rnQ, rnK);
    split_t<<<dim3(36, 4, BATCH * 2), 256, 0, stream>>>(lr, refsr, Qhi, Qlo, Khi, Klo);

    gemm_g<<<dim3(18, 36, BATCH), 256, 0, stream>>>(Khi, Klo, Qhi, Qlo, G);
    stencil_R<<<dim3(576, BATCH), 576, 0, stream>>>(G, rnK, rnQ, R);

    argmax_part<<<dim3(9, NSEG, BATCH), 256, 0, stream>>>(R, apv, api);
    argmax_merge<<<dim3(9, BATCH), 256, 0, stream>>>(apv, api, hidx);
    top3_part<<<dim3(9, NSEG, BATCH), 256, 0, stream>>>(R, hidx, pv, pr);
    top3_merge<<<dim3(9, BATCH), 256, 0, stream>>>(pv, pr, out, effp);

    fold_t3<<<4608,  192, 0, stream>>>(ref3, effp, out + OFF_T3);
    fold_t2<<<13824, 256, 0, stream>>>(ref2, effp, out + OFF_T2);
    fold_t1<<<13824, 256, 0, stream>>>(ref1, effp, out + OFF_T1);
}

// Round 2
// 551.366 us; speedup vs baseline: 1.3880x; 1.1672x over previous
//
#include <hip/hip_runtime.h>
#include <math.h>

// Problem constants
#define BATCH 2
#define C3 256
#define C2 128
#define C1 64
#define HH 48
#define WW 48
#define L 2304          // 48*48 unfold positions
#define GK 256          // channel dim for G-GEMM
#define BK2 64          // K-tile (bf16) for G-GEMM
#define NSEG 16
#define SEG 144         // 2304/16

// Output flat offsets (float elements)
#define OFF_T3 13824
#define OFF_T2 3552768
#define OFF_T1 10630656

typedef __bf16 bf16x8 __attribute__((ext_vector_type(8)));
typedef float  f32x4  __attribute__((ext_vector_type(4)));
typedef float  f32x2  __attribute__((ext_vector_type(2)));
// dword-aligned (not 16B) float4 for shifted stencil loads
typedef float  f32x4u __attribute__((ext_vector_type(4), aligned(4)));

__device__ __forceinline__ void gload16(const void* g, void* l) {
    __builtin_amdgcn_global_load_lds(
        (const __attribute__((address_space(1))) void*)g,
        (__attribute__((address_space(3))) void*)l, 16, 0, 0);
}

__device__ __forceinline__ void nts4(float* p, float a, float b, float c, float d) {
    f32x4 v = {a, b, c, d};
    __builtin_nontemporal_store(v, (f32x4*)p);
}
__device__ __forceinline__ void nts2(float* p, float a, float b) {
    f32x2 v = {a, b};
    __builtin_nontemporal_store(v, (f32x2*)p);
}

// ---------------- per-pixel channel sum of squares (both images) ----------------
__global__ void ssq_kernel(const float* __restrict__ lr, const float* __restrict__ refsr,
                           float* __restrict__ ssQ, float* __restrict__ ssK) {
    int idx = blockIdx.x * 256 + threadIdx.x;
    if (idx >= BATCH * L) return;
    const float* img = blockIdx.y ? refsr : lr;
    float* ss = blockIdx.y ? ssK : ssQ;
    int b = idx / L, yx = idx % L;
    const float* p = img + (size_t)b * C3 * L + yx;
    float s = 0.f;
    #pragma unroll 4
    for (int c = 0; c < C3; ++c) { float v = p[(size_t)c * L]; s += v * v; }
    ss[idx] = s;
}

// ---------------- 3x3 window sum -> 1/max(sqrt, eps) (both) ----------------
__global__ void norm_kernel(const float* __restrict__ ssQ, const float* __restrict__ ssK,
                            float* __restrict__ rnQ, float* __restrict__ rnK) {
    int idx = blockIdx.x * 256 + threadIdx.x;
    if (idx >= BATCH * L) return;
    const float* ss = blockIdx.y ? ssK : ssQ;
    float* rn = blockIdx.y ? rnK : rnQ;
    int b = idx / L, l = idx % L;
    int ly = l / WW, lx = l % WW;
    const float* s = ss + b * L;
    float acc = 0.f;
    #pragma unroll
    for (int dy = -1; dy <= 1; ++dy) {
        int yy = ly + dy;
        if ((unsigned)yy >= (unsigned)HH) continue;
        #pragma unroll
        for (int dx = -1; dx <= 1; ++dx) {
            int xx = lx + dx;
            if ((unsigned)xx >= (unsigned)WW) continue;
            acc += s[yy * WW + xx];
        }
    }
    float n = sqrtf(acc);
    n = fmaxf(n, 1e-12f);
    rn[idx] = 1.0f / n;
}

// ---------------- transpose [C][pix] -> [pix][C] + bf16 hi/lo split (both images) ----
// grid: (36 u-tiles, 4 c-tiles, B*2); 64x64 fp32 tile via LDS.
__global__ __launch_bounds__(256) void split_t(const float* __restrict__ lr,
                                               const float* __restrict__ refsr,
                                               __bf16* __restrict__ Qhi, __bf16* __restrict__ Qlo,
                                               __bf16* __restrict__ Khi, __bf16* __restrict__ Klo) {
    __shared__ float tile[64][65];
    int bz = blockIdx.z;
    int b = bz >> 1;
    const float* img = (bz & 1) ? refsr : lr;
    __bf16* dh = (bz & 1) ? Khi : Qhi;
    __bf16* dl = (bz & 1) ? Klo : Qlo;
    int u0 = blockIdx.x * 64, c0 = blockIdx.y * 64;
    int t = threadIdx.x;
    {
        int ul = t & 63, cl0 = t >> 6;
        const float* src = img + ((size_t)b * C3 + c0) * L + u0;
        #pragma unroll
        for (int r = 0; r < 16; ++r) {
            int cl = cl0 + r * 4;
            tile[cl][ul] = src[(size_t)cl * L + ul];
        }
    }
    __syncthreads();
    {
        int cl = t & 63, ul0 = t >> 6;
        __bf16* oh = dh + ((size_t)b * L + u0) * GK + c0 + cl;
        __bf16* ol = dl + ((size_t)b * L + u0) * GK + c0 + cl;
        #pragma unroll
        for (int r = 0; r < 16; ++r) {
            int ul = ul0 + r * 4;
            float v = tile[cl][ul];
            __bf16 h = (__bf16)v;
            float lo = v - (float)h;
            oh[(size_t)ul * GK] = h;
            ol[(size_t)ul * GK] = (__bf16)lo;
        }
    }
}

// ---------------- split-bf16 MFMA GEMM NT over K=256: G[u,v] ----------------
// 64(u) x 128(v) tiles, BK=64. LDS XOR-swizzle (slot ^= row&7) applied on BOTH
// the global source address (gload_lds writes linearly) and the ds_read slot.
// G stored with NORMAL (cached) stores: it is consumed immediately by stencil_R,
// and NT stores were forcing stencil reads out to HBM (FETCH_SIZE 108MB).
__global__ __launch_bounds__(256) void gemm_g(const __bf16* __restrict__ Khi,
                                              const __bf16* __restrict__ Klo,
                                              const __bf16* __restrict__ Qhi,
                                              const __bf16* __restrict__ Qlo,
                                              float* __restrict__ Gg) {
    __shared__ __align__(16) __bf16 Ah[64 * BK2];
    __shared__ __align__(16) __bf16 Al[64 * BK2];
    __shared__ __align__(16) __bf16 Bh[128 * BK2];
    __shared__ __align__(16) __bf16 Bl[128 * BK2];
    int t = threadIdx.x;
    int lane = t & 63;
    int wv = t >> 6;
    int b = blockIdx.z;
    size_t ioff = (size_t)b * L * GK;
    const __bf16* Ahg = Khi + ioff;   // rows u (refsr)
    const __bf16* Alg = Klo + ioff;
    const __bf16* Bhg = Qhi + ioff;   // rows v (lr)
    const __bf16* Blg = Qlo + ioff;
    int m0 = blockIdx.x * 128;
    int l0 = blockIdx.y * 64;
    int wl = wv >> 1, wm = wv & 1;    // wave tile: 32(u) x 64(v)
    int q = lane >> 4, r16 = lane & 15;

    f32x4 acc[2][4];
    #pragma unroll
    for (int i = 0; i < 2; i++)
        #pragma unroll
        for (int j = 0; j < 4; j++) acc[i][j] = (f32x4)(0.f);

    for (int k0 = 0; k0 < GK; k0 += BK2) {
        #pragma unroll
        for (int hh = 0; hh < 2; ++hh) {          // A: 512 chunks of 16B
            int c = t + hh * 256;
            int row = c >> 3, qo = c & 7;
            size_t ga = (size_t)(l0 + row) * GK + k0 + ((qo ^ (row & 7)) * 8);
            gload16(Ahg + ga, &Ah[c * 8]);
            gload16(Alg + ga, &Al[c * 8]);
        }
        #pragma unroll
        for (int hh = 0; hh < 4; ++hh) {          // B: 1024 chunks
            int c = t + hh * 256;
            int row = c >> 3, qo = c & 7;
            size_t gb = (size_t)(m0 + row) * GK + k0 + ((qo ^ (row & 7)) * 8);
            gload16(Bhg + gb, &Bh[c * 8]);
            gload16(Blg + gb, &Bl[c * 8]);
        }
        __syncthreads();

        #pragma unroll
        for (int h = 0; h < 2; ++h) {             // two k-32 halves of BK=64
            bf16x8 ah[2], al[2], bh[4], bl[4];
            #pragma unroll
            for (int i = 0; i < 2; ++i) {
                int row = wl * 32 + i * 16 + r16;
                int ch = (h * 4 + q) ^ (row & 7);
                ah[i] = *(const bf16x8*)&Ah[row * BK2 + ch * 8];
                al[i] = *(const bf16x8*)&Al[row * BK2 + ch * 8];
            }
            #pragma unroll
            for (int j = 0; j < 4; ++j) {
                int row = wm * 64 + j * 16 + r16;
                int ch = (h * 4 + q) ^ (row & 7);
                bh[j] = *(const bf16x8*)&Bh[row * BK2 + ch * 8];
                bl[j] = *(const bf16x8*)&Bl[row * BK2 + ch * 8];
            }
            #pragma unroll
            for (int i = 0; i < 2; ++i)
                #pragma unroll
                for (int j = 0; j < 4; ++j) {
                    acc[i][j] = __builtin_amdgcn_mfma_f32_16x16x32_bf16(ah[i], bh[j], acc[i][j], 0, 0, 0);
                    acc[i][j] = __builtin_amdgcn_mfma_f32_16x16x32_bf16(ah[i], bl[j], acc[i][j], 0, 0, 0);
                    acc[i][j] = __builtin_amdgcn_mfma_f32_16x16x32_bf16(al[i], bh[j], acc[i][j], 0, 0, 0);
                }
        }
        __syncthreads();
    }

    float* Cb = Gg + (size_t)b * L * L;
    #pragma unroll
    for (int i = 0; i < 2; ++i) {
        int rowb = l0 + wl * 32 + i * 16 + q * 4;
        #pragma unroll
        for (int j = 0; j < 4; ++j) {
            int col = m0 + wm * 64 + j * 16 + r16;
            #pragma unroll
            for (int r = 0; r < 4; ++r)
                Cb[(size_t)(rowb + r) * L + col] = acc[i][j][r];
        }
    }
}

// ---------------- R[l,m] = rnK[l]*rnQ[m]*sum_{9 diag shifts} G[l+s, m+s] ----------------
// grid: 1152 blocks (XCD-chunked: each XCD owns a contiguous 576-row l-range so the
// +-49-row halo bands stay in its L2). Block = 4 rows l, thread = 4 cols m.
// Loads are dword-aligned float4 (9 per row instead of 36 scalars); masked lanes
// may read a few bytes into the adjacent workspace region (R / Khi) - values are
// select-ed away, addresses stay inside the workspace.
__global__ __launch_bounds__(576) void stencil_R(const float* __restrict__ G,
                                                 const float* __restrict__ rnK,
                                                 const float* __restrict__ rnQ,
                                                 float* __restrict__ R) {
    int blk = blockIdx.x;                 // 0..1151
    int xcd = blk & 7, idx = blk >> 3;    // 144 chunks per XCD
    int gc = xcd * 144 + idx;             // contiguous l-chunks per XCD
    int b = gc / 576;
    int lbase = (gc % 576) * 4;
    int m0 = threadIdx.x * 4;
    const float* Gb = G + (size_t)b * L * L;
    int mdiv0 = m0 / 48, mmod0 = m0 % 48; // 4 cols never straddle a 48-boundary
    const float* rq = rnQ + b * L + m0;
    float rqv0 = rq[0], rqv1 = rq[1], rqv2 = rq[2], rqv3 = rq[3];

    #pragma unroll
    for (int li = 0; li < 4; ++li) {
        int l = lbase + li;
        int ly = l / 48, lx = l % 48;
        float a0 = 0.f, a1 = 0.f, a2 = 0.f, a3 = 0.f;
        #pragma unroll
        for (int dy = -1; dy <= 1; ++dy) {
            if ((unsigned)(ly + dy) >= 48u) continue;
            if ((unsigned)(mdiv0 + dy) >= 48u) continue;    // uniform over the 4 cols
            #pragma unroll
            for (int dx = -1; dx <= 1; ++dx) {
                if ((unsigned)(lx + dx) >= 48u) continue;
                int s = dy * 48 + dx;
                f32x4u v = *(const f32x4u*)(Gb + (size_t)(l + s) * L + s + m0);
                bool e0 = (unsigned)(mmod0 + dx) < 48u;     // only j=0,dx=-1 can fail
                bool e3 = (unsigned)(mmod0 + 3 + dx) < 48u; // only j=3,dx=+1 can fail
                a0 += e0 ? v[0] : 0.f;
                a1 += v[1];
                a2 += v[2];
                a3 += e3 ? v[3] : 0.f;
            }
        }
        float rk = rnK[b * L + l];
        f32x4 o = { a0 * rk * rqv0, a1 * rk * rqv1, a2 * rk * rqv2, a3 * rk * rqv3 };
        *(f32x4*)(R + (size_t)b * L * L + (size_t)l * L + m0) = o;  // cached: re-read by argmax/top3
    }
}

// ---------------- segmented argmax over l (ties -> lowest l) ----------------
__global__ void argmax_part(const float* __restrict__ R, float* __restrict__ pv, int* __restrict__ pi) {
    int m = blockIdx.x * 256 + threadIdx.x;
    int seg = blockIdx.y, b = blockIdx.z;
    const float* Rb = R + (size_t)b * L * L;
    float bv = -3.4e38f; int bi = 0;
    int l0 = seg * SEG;
    #pragma unroll 4
    for (int j = 0; j < SEG; j++) {
        float v = Rb[(size_t)(l0 + j) * L + m];
        if (v > bv) { bv = v; bi = l0 + j; }
    }
    int o = (b * NSEG + seg) * L + m;
    pv[o] = bv; pi[o] = bi;
}

__global__ void argmax_merge(const float* __restrict__ pv, const int* __restrict__ pi,
                             int* __restrict__ hidx) {
    int m = blockIdx.x * 256 + threadIdx.x;
    int b = blockIdx.y;
    float bv = -3.4e38f; int bi = 0;
    #pragma unroll
    for (int s = 0; s < NSEG; s++) {
        int o = (b * NSEG + s) * L + m;
        float v = pv[o];
        if (v > bv) { bv = v; bi = pi[o]; }
    }
    hidx[b * L + m] = bi;
}

// ---------------- segmented top-3 of s_l = R[hidx[l], m] ----------------
__global__ void top3_part(const float* __restrict__ R, const int* __restrict__ hidx,
                          float* __restrict__ pv, int* __restrict__ pr) {
    int m = blockIdx.x * 256 + threadIdx.x;
    int seg = blockIdx.y, b = blockIdx.z;
    const float* Rb = R + (size_t)b * L * L;
    __shared__ int hrow_s[SEG];
    if (threadIdx.x < SEG) hrow_s[threadIdx.x] = hidx[b * L + seg * SEG + threadIdx.x];
    __syncthreads();
    float v0 = -3.4e38f, v1 = -3.4e38f, v2 = -3.4e38f;
    int r0 = 0, r1 = 0, r2 = 0;
    #pragma unroll 4
    for (int j = 0; j < SEG; j++) {
        int row = hrow_s[j];
        float v = Rb[(size_t)row * L + m];
        if (v > v0)      { v2 = v1; r2 = r1; v1 = v0; r1 = r0; v0 = v; r0 = row; }
        else if (v > v1) { v2 = v1; r2 = r1; v1 = v;  r1 = row; }
        else if (v > v2) { v2 = v;  r2 = row; }
    }
    size_t o = ((size_t)(b * NSEG + seg) * 3) * L + m;
    pv[o] = v0; pv[o + L] = v1; pv[o + 2 * L] = v2;
    pr[o] = r0; pr[o + L] = r1; pr[o + 2 * L] = r2;
}

__global__ void top3_merge(const float* __restrict__ pv, const int* __restrict__ pr,
                           float* __restrict__ outS, int* __restrict__ effp) {
    int m = blockIdx.x * 256 + threadIdx.x;
    int b = blockIdx.y;
    float v0 = -3.4e38f, v1 = -3.4e38f, v2 = -3.4e38f;
    int r0 = 0, r1 = 0, r2 = 0;
    for (int s = 0; s < NSEG; s++) {
        size_t o = ((size_t)(b * NSEG + s) * 3) * L + m;
        #pragma unroll
        for (int j = 0; j < 3; j++) {
            float v = pv[o + (size_t)j * L];
            int r = pr[o + (size_t)j * L];
            if (v > v0)      { v2 = v1; r2 = r1; v1 = v0; r1 = r0; v0 = v; r0 = r; }
            else if (v > v1) { v2 = v1; r2 = r1; v1 = v;  r1 = r; }
            else if (v > v2) { v2 = v;  r2 = r; }
        }
    }
    outS[(0 * BATCH + b) * L + m] = v0;
    outS[(1 * BATCH + b) * L + m] = v1;
    outS[(2 * BATCH + b) * L + m] = v2;
    effp[(b * 3 + 0) * L + m] = ((r0 / 48) << 8) | (r0 % 48);
    effp[(b * 3 + 1) * L + m] = ((r1 / 48) << 8) | (r1 % 48);
    effp[(b * 3 + 2) * L + m] = ((r2 / 48) << 8) | (r2 % 48);
}

// ---------------- folds, XCD-swizzled so one (b,c) plane stays on one XCD's L2 ----------
__global__ __launch_bounds__(256) void fold_t1(const float* __restrict__ ref, const int* __restrict__ effp,
                                               float* __restrict__ outT) {
    const int W = 192;
    int blk = blockIdx.x;
    int xcd = blk & 7;
    int r = blk >> 3;
    int tile = r % 36;
    int rr = r / 36;
    int i = rr % 3;
    int pw = rr / 3;                  // 0..15
    int plane = xcd + 8 * pw;         // 0..127
    int b = plane >> 6, c = plane & 63;
    int id = tile * 256 + threadIdx.x;     // y*48 + qx in [0, 9216)
    int y = id / 48, qx = id % 48;
    int qy = y >> 2, ry = y & 3;
    const int* e = effp + (b * 3 + i) * L;
    const float* src = ref + ((size_t)b * C1 + c) * (W * W);
    float4 s = make_float4(0.f, 0.f, 0.f, 0.f);
    #pragma unroll
    for (int dh = -1; dh <= 1; ++dh) {
        int ho = qy + dh;
        if ((unsigned)ho >= 48u) continue;
        #pragma unroll
        for (int dw = -1; dw <= 1; ++dw) {
            int wo = qx + dw;
            if ((unsigned)wo >= 48u) continue;
            int ep = e[ho * 48 + wo];
            int yq = (ep >> 8) - dh, xq = (ep & 255) - dw;
            if ((unsigned)yq >= 48u || (unsigned)xq >= 48u) continue;
            const float4 v = *(const float4*)(src + (yq * 4 + ry) * W + xq * 4);
            s.x += v.x; s.y += v.y; s.z += v.z; s.w += v.w;
        }
    }
    const float k = 1.0f / 9.0f;
    nts4(outT + (((size_t)i * BATCH + b) * C1 + c) * (size_t)(W * W) + y * W + qx * 4,
         s.x * k, s.y * k, s.z * k, s.w * k);
}

__global__ __launch_bounds__(256) void fold_t2(const float* __restrict__ ref, const int* __restrict__ effp,
                                               float* __restrict__ outT) {
    const int W = 96;
    int blk = blockIdx.x;
    int xcd = blk & 7;
    int r = blk >> 3;
    int tile = r % 18;
    int rr = r / 18;
    int i = rr % 3;
    int pw = rr / 3;                  // 0..31
    int plane = xcd + 8 * pw;         // 0..255
    int b = plane >> 7, c = plane & 127;
    int id = tile * 256 + threadIdx.x;     // y*48 + qx in [0, 4608)
    int y = id / 48, qx = id % 48;
    int qy = y >> 1, ry = y & 1;
    const int* e = effp + (b * 3 + i) * L;
    const float* src = ref + ((size_t)b * C2 + c) * (W * W);
    float2 s = make_float2(0.f, 0.f);
    #pragma unroll
    for (int dh = -1; dh <= 1; ++dh) {
        int ho = qy + dh;
        if ((unsigned)ho >= 48u) continue;
        #pragma unroll
        for (int dw = -1; dw <= 1; ++dw) {
            int wo = qx + dw;
            if ((unsigned)wo >= 48u) continue;
            int ep = e[ho * 48 + wo];
            int yq = (ep >> 8) - dh, xq = (ep & 255) - dw;
            if ((unsigned)yq >= 48u || (unsigned)xq >= 48u) continue;
            const float2 v = *(const float2*)(src + (yq * 2 + ry) * W + xq * 2);
            s.x += v.x; s.y += v.y;
        }
    }
    const float k = 1.0f / 9.0f;
    nts2(outT + (((size_t)i * BATCH + b) * C2 + c) * (size_t)(W * W) + y * W + qx * 2,
         s.x * k, s.y * k);
}

__global__ __launch_bounds__(192) void fold_t3(const float* __restrict__ ref, const int* __restrict__ effp,
                                               float* __restrict__ outT) {
    const int W = 48;
    int blk = blockIdx.x;
    int xcd = blk & 7;
    int r = blk >> 3;
    int tile = r % 3;
    int rr = r / 3;
    int i = rr % 3;
    int pw = rr / 3;                  // 0..63
    int plane = xcd + 8 * pw;         // 0..511
    int b = plane >> 8, c = plane & 255;
    int id = tile * 192 + threadIdx.x;     // y*12 + xq in [0, 576)
    int y = id / 12, x0 = (id % 12) * 4;
    const int* e = effp + (b * 3 + i) * L;
    const float* src = ref + ((size_t)b * C3 + c) * (W * W);
    float s[4] = {0.f, 0.f, 0.f, 0.f};
    #pragma unroll
    for (int dh = -1; dh <= 1; ++dh) {
        int ho = y + dh;
        if ((unsigned)ho >= 48u) continue;
        int ep6[6];
        #pragma unroll
        for (int j = 0; j < 6; ++j) {
            int wo = x0 - 1 + j;
            ep6[j] = ((unsigned)wo < 48u) ? e[ho * 48 + wo] : -1;
        }
        #pragma unroll
        for (int xi = 0; xi < 4; ++xi) {
            #pragma unroll
            for (int dw = -1; dw <= 1; ++dw) {
                int ep = ep6[xi + dw + 1];
                if (ep < 0) continue;
                int yy = (ep >> 8) - dh, xx = (ep & 255) - dw;
                if ((unsigned)yy >= 48u || (unsigned)xx >= 48u) continue;
                s[xi] += src[yy * W + xx];
            }
        }
    }
    const float k = 1.0f / 9.0f;
    nts4(outT + (((size_t)i * BATCH + b) * C3 + c) * (size_t)(W * W) + y * W + x0,
         s[0] * k, s[1] * k, s[2] * k, s[3] * k);
}

extern "C" void kernel_launch(void* const* d_in, const int* in_sizes, int n_in,
                              void* d_out, int out_size, void* d_ws, size_t ws_size,
                              hipStream_t stream) {
    const float* lr    = (const float*)d_in[0];
    const float* refsr = (const float*)d_in[1];
    const float* ref1  = (const float*)d_in[2];
    const float* ref2  = (const float*)d_in[3];
    const float* ref3  = (const float*)d_in[4];
    float* out = (float*)d_out;

    float*  R   = (float*)d_ws;                              // B*L*L fp32
    float*  G   = R + (size_t)BATCH * L * L;                 // B*L*L fp32
    __bf16* Khi = (__bf16*)(G + (size_t)BATCH * L * L);      // B*L*GK bf16 each
    __bf16* Klo = Khi + (size_t)BATCH * L * GK;
    __bf16* Qhi = Klo + (size_t)BATCH * L * GK;
    __bf16* Qlo = Qhi + (size_t)BATCH * L * GK;
    float* ssQ = (float*)(Qlo + (size_t)BATCH * L * GK);
    float* ssK = ssQ + BATCH * L;
    float* rnQ = ssK + BATCH * L;
    float* rnK = rnQ + BATCH * L;
    float* apv = rnK + BATCH * L;
    float* pv  = apv + BATCH * NSEG * L;
    int*   api = (int*)(pv + (size_t)BATCH * NSEG * 3 * L);
    int*   pr  = api + BATCH * NSEG * L;
    int*   hidx = pr + (size_t)BATCH * NSEG * 3 * L;
    int*   effp = hidx + BATCH * L;

    ssq_kernel<<<dim3(18, 2), 256, 0, stream>>>(lr, refsr, ssQ, ssK);
    norm_kernel<<<dim3(18, 2), 256, 0, stream>>>(ssQ, ssK, rnQ, rnK);
    split_t<<<dim3(36, 4, BATCH * 2), 256, 0, stream>>>(lr, refsr, Qhi, Qlo, Khi, Klo);

    gemm_g<<<dim3(18, 36, BATCH), 256, 0, stream>>>(Khi, Klo, Qhi, Qlo, G);
    stencil_R<<<1152, 576, 0, stream>>>(G, rnK, rnQ, R);

    argmax_part<<<dim3(9, NSEG, BATCH), 256, 0, stream>>>(R, apv, api);
    argmax_merge<<<dim3(9, BATCH), 256, 0, stream>>>(apv, api, hidx);
    top3_part<<<dim3(9, NSEG, BATCH), 256, 0, stream>>>(R, hidx, pv, pr);
    top3_merge<<<dim3(9, BATCH), 256, 0, stream>>>(pv, pr, out, effp);

    fold_t3<<<4608,  192, 0, stream>>>(ref3, effp, out + OFF_T3);
    fold_t2<<<13824, 256, 0, stream>>>(ref2, effp, out + OFF_T2);
    fold_t1<<<13824, 256, 0, stream>>>(ref1, effp, out + OFF_T1);
}

// Round 3
// 486.013 us; speedup vs baseline: 1.5746x; 1.1345x over previous
//
#include <hip/hip_runtime.h>
#include <math.h>

// Problem constants
#define BATCH 2
#define C3 256
#define C2 128
#define C1 64
#define HH 48
#define WW 48
#define L 2304          // 48*48 unfold positions
#define GK 256          // channel dim for G-GEMM
#define BK2 64          // K-tile (bf16) for G-GEMM
#define NSEG 16
#define SEG 144         // 2304/16

// Output flat offsets (float elements)
#define OFF_T3 13824
#define OFF_T2 3552768
#define OFF_T1 10630656

typedef __bf16 bf16x8 __attribute__((ext_vector_type(8)));
typedef float  f32x4  __attribute__((ext_vector_type(4)));
typedef float  f32x2  __attribute__((ext_vector_type(2)));
// dword-aligned (not 16B) float4 for shifted stencil loads
typedef float  f32x4u __attribute__((ext_vector_type(4), aligned(4)));

__device__ __forceinline__ void gload16(const void* g, void* l) {
    __builtin_amdgcn_global_load_lds(
        (const __attribute__((address_space(1))) void*)g,
        (__attribute__((address_space(3))) void*)l, 16, 0, 0);
}

__device__ __forceinline__ void nts4(float* p, float a, float b, float c, float d) {
    f32x4 v = {a, b, c, d};
    __builtin_nontemporal_store(v, (f32x4*)p);
}
__device__ __forceinline__ void nts2(float* p, float a, float b) {
    f32x2 v = {a, b};
    __builtin_nontemporal_store(v, (f32x2*)p);
}

// ---------------- per-pixel channel sum of squares (both images) ----------------
__global__ void ssq_kernel(const float* __restrict__ lr, const float* __restrict__ refsr,
                           float* __restrict__ ssQ, float* __restrict__ ssK) {
    int idx = blockIdx.x * 256 + threadIdx.x;
    if (idx >= BATCH * L) return;
    const float* img = blockIdx.y ? refsr : lr;
    float* ss = blockIdx.y ? ssK : ssQ;
    int b = idx / L, yx = idx % L;
    const float* p = img + (size_t)b * C3 * L + yx;
    float s = 0.f;
    #pragma unroll 4
    for (int c = 0; c < C3; ++c) { float v = p[(size_t)c * L]; s += v * v; }
    ss[idx] = s;
}

// ---------------- 3x3 window sum -> 1/max(sqrt, eps) (both) ----------------
__global__ void norm_kernel(const float* __restrict__ ssQ, const float* __restrict__ ssK,
                            float* __restrict__ rnQ, float* __restrict__ rnK) {
    int idx = blockIdx.x * 256 + threadIdx.x;
    if (idx >= BATCH * L) return;
    const float* ss = blockIdx.y ? ssK : ssQ;
    float* rn = blockIdx.y ? rnK : rnQ;
    int b = idx / L, l = idx % L;
    int ly = l / WW, lx = l % WW;
    const float* s = ss + b * L;
    float acc = 0.f;
    #pragma unroll
    for (int dy = -1; dy <= 1; ++dy) {
        int yy = ly + dy;
        if ((unsigned)yy >= (unsigned)HH) continue;
        #pragma unroll
        for (int dx = -1; dx <= 1; ++dx) {
            int xx = lx + dx;
            if ((unsigned)xx >= (unsigned)WW) continue;
            acc += s[yy * WW + xx];
        }
    }
    float n = sqrtf(acc);
    n = fmaxf(n, 1e-12f);
    rn[idx] = 1.0f / n;
}

// ---------------- transpose [C][pix] -> [pix][C] + bf16 hi/lo split (both images) ----
__global__ __launch_bounds__(256) void split_t(const float* __restrict__ lr,
                                               const float* __restrict__ refsr,
                                               __bf16* __restrict__ Qhi, __bf16* __restrict__ Qlo,
                                               __bf16* __restrict__ Khi, __bf16* __restrict__ Klo) {
    __shared__ float tile[64][65];
    int bz = blockIdx.z;
    int b = bz >> 1;
    const float* img = (bz & 1) ? refsr : lr;
    __bf16* dh = (bz & 1) ? Khi : Qhi;
    __bf16* dl = (bz & 1) ? Klo : Qlo;
    int u0 = blockIdx.x * 64, c0 = blockIdx.y * 64;
    int t = threadIdx.x;
    {
        int ul = t & 63, cl0 = t >> 6;
        const float* src = img + ((size_t)b * C3 + c0) * L + u0;
        #pragma unroll
        for (int r = 0; r < 16; ++r) {
            int cl = cl0 + r * 4;
            tile[cl][ul] = src[(size_t)cl * L + ul];
        }
    }
    __syncthreads();
    {
        int cl = t & 63, ul0 = t >> 6;
        __bf16* oh = dh + ((size_t)b * L + u0) * GK + c0 + cl;
        __bf16* ol = dl + ((size_t)b * L + u0) * GK + c0 + cl;
        #pragma unroll
        for (int r = 0; r < 16; ++r) {
            int ul = ul0 + r * 4;
            float v = tile[cl][ul];
            __bf16 h = (__bf16)v;
            float lo = v - (float)h;
            oh[(size_t)ul * GK] = h;
            ol[(size_t)ul * GK] = (__bf16)lo;
        }
    }
}

// ---------------- patch-major re-layouts for the fold gather sources ----------------
// ref1 [b][c][192][192] -> ref1p [(b*64+c)*2304 + qy*48+qx][4][4]  (64B/patch, line-aligned)
__global__ __launch_bounds__(256) void t1prep(const float* __restrict__ ref, float* __restrict__ refp) {
    int id = blockIdx.x * 256 + threadIdx.x;     // 294912 patches
    int qx = id % 48, t = id / 48;
    int qy = t % 48, pc = t / 48;                // pc = b*64+c
    const float* src = ref + (size_t)pc * (192 * 192) + (qy * 4) * 192 + qx * 4;
    float* dst = refp + (size_t)id * 16;
    #pragma unroll
    for (int r = 0; r < 4; ++r) {
        f32x4 v = *(const f32x4*)(src + r * 192);
        *(f32x4*)(dst + r * 4) = v;
    }
}

// ref2 [b][c][96][96] -> ref2p [(b*128+c)*2304 + qy*48+qx][2][2]  (16B/patch)
__global__ __launch_bounds__(256) void t2prep(const float* __restrict__ ref, float* __restrict__ refp) {
    int id = blockIdx.x * 256 + threadIdx.x;     // 589824 patches
    int qx = id % 48, t = id / 48;
    int qy = t % 48, pc = t / 48;                // pc = b*128+c
    const float* src = ref + (size_t)pc * (96 * 96) + (qy * 2) * 96 + qx * 2;
    f32x2 a = *(const f32x2*)(src);
    f32x2 b2 = *(const f32x2*)(src + 96);
    f32x4 v = { a[0], a[1], b2[0], b2[1] };
    *(f32x4*)(refp + (size_t)id * 4) = v;
}

// ---------------- split-bf16 MFMA GEMM NT over K=256: G[u,v] ----------------
__global__ __launch_bounds__(256) void gemm_g(const __bf16* __restrict__ Khi,
                                              const __bf16* __restrict__ Klo,
                                              const __bf16* __restrict__ Qhi,
                                              const __bf16* __restrict__ Qlo,
                                              float* __restrict__ Gg) {
    __shared__ __align__(16) __bf16 Ah[64 * BK2];
    __shared__ __align__(16) __bf16 Al[64 * BK2];
    __shared__ __align__(16) __bf16 Bh[128 * BK2];
    __shared__ __align__(16) __bf16 Bl[128 * BK2];
    int t = threadIdx.x;
    int lane = t & 63;
    int wv = t >> 6;
    int b = blockIdx.z;
    size_t ioff = (size_t)b * L * GK;
    const __bf16* Ahg = Khi + ioff;   // rows u (refsr)
    const __bf16* Alg = Klo + ioff;
    const __bf16* Bhg = Qhi + ioff;   // rows v (lr)
    const __bf16* Blg = Qlo + ioff;
    int m0 = blockIdx.x * 128;
    int l0 = blockIdx.y * 64;
    int wl = wv >> 1, wm = wv & 1;    // wave tile: 32(u) x 64(v)
    int q = lane >> 4, r16 = lane & 15;

    f32x4 acc[2][4];
    #pragma unroll
    for (int i = 0; i < 2; i++)
        #pragma unroll
        for (int j = 0; j < 4; j++) acc[i][j] = (f32x4)(0.f);

    for (int k0 = 0; k0 < GK; k0 += BK2) {
        #pragma unroll
        for (int hh = 0; hh < 2; ++hh) {          // A: 512 chunks of 16B
            int c = t + hh * 256;
            int row = c >> 3, qo = c & 7;
            size_t ga = (size_t)(l0 + row) * GK + k0 + ((qo ^ (row & 7)) * 8);
            gload16(Ahg + ga, &Ah[c * 8]);
            gload16(Alg + ga, &Al[c * 8]);
        }
        #pragma unroll
        for (int hh = 0; hh < 4; ++hh) {          // B: 1024 chunks
            int c = t + hh * 256;
            int row = c >> 3, qo = c & 7;
            size_t gb = (size_t)(m0 + row) * GK + k0 + ((qo ^ (row & 7)) * 8);
            gload16(Bhg + gb, &Bh[c * 8]);
            gload16(Blg + gb, &Bl[c * 8]);
        }
        __syncthreads();

        #pragma unroll
        for (int h = 0; h < 2; ++h) {             // two k-32 halves of BK=64
            bf16x8 ah[2], al[2], bh[4], bl[4];
            #pragma unroll
            for (int i = 0; i < 2; ++i) {
                int row = wl * 32 + i * 16 + r16;
                int ch = (h * 4 + q) ^ (row & 7);
                ah[i] = *(const bf16x8*)&Ah[row * BK2 + ch * 8];
                al[i] = *(const bf16x8*)&Al[row * BK2 + ch * 8];
            }
            #pragma unroll
            for (int j = 0; j < 4; ++j) {
                int row = wm * 64 + j * 16 + r16;
                int ch = (h * 4 + q) ^ (row & 7);
                bh[j] = *(const bf16x8*)&Bh[row * BK2 + ch * 8];
                bl[j] = *(const bf16x8*)&Bl[row * BK2 + ch * 8];
            }
            #pragma unroll
            for (int i = 0; i < 2; ++i)
                #pragma unroll
                for (int j = 0; j < 4; ++j) {
                    acc[i][j] = __builtin_amdgcn_mfma_f32_16x16x32_bf16(ah[i], bh[j], acc[i][j], 0, 0, 0);
                    acc[i][j] = __builtin_amdgcn_mfma_f32_16x16x32_bf16(ah[i], bl[j], acc[i][j], 0, 0, 0);
                    acc[i][j] = __builtin_amdgcn_mfma_f32_16x16x32_bf16(al[i], bh[j], acc[i][j], 0, 0, 0);
                }
        }
        __syncthreads();
    }

    float* Cb = Gg + (size_t)b * L * L;
    #pragma unroll
    for (int i = 0; i < 2; ++i) {
        int rowb = l0 + wl * 32 + i * 16 + q * 4;
        #pragma unroll
        for (int j = 0; j < 4; ++j) {
            int col = m0 + wm * 64 + j * 16 + r16;
            #pragma unroll
            for (int r = 0; r < 4; ++r)
                Cb[(size_t)(rowb + r) * L + col] = acc[i][j][r];
        }
    }
}

// ---------------- R[l,m] = rnK[l]*rnQ[m]*sum_{9 diag shifts} G[l+s, m+s] ----------------
__global__ __launch_bounds__(576) void stencil_R(const float* __restrict__ G,
                                                 const float* __restrict__ rnK,
                                                 const float* __restrict__ rnQ,
                                                 float* __restrict__ R) {
    int blk = blockIdx.x;                 // 0..1151
    int xcd = blk & 7, idx = blk >> 3;    // 144 chunks per XCD
    int gc = xcd * 144 + idx;             // contiguous l-chunks per XCD
    int b = gc / 576;
    int lbase = (gc % 576) * 4;
    int m0 = threadIdx.x * 4;
    const float* Gb = G + (size_t)b * L * L;
    int mdiv0 = m0 / 48, mmod0 = m0 % 48; // 4 cols never straddle a 48-boundary
    const float* rq = rnQ + b * L + m0;
    float rqv0 = rq[0], rqv1 = rq[1], rqv2 = rq[2], rqv3 = rq[3];

    #pragma unroll
    for (int li = 0; li < 4; ++li) {
        int l = lbase + li;
        int ly = l / 48, lx = l % 48;
        float a0 = 0.f, a1 = 0.f, a2 = 0.f, a3 = 0.f;
        #pragma unroll
        for (int dy = -1; dy <= 1; ++dy) {
            if ((unsigned)(ly + dy) >= 48u) continue;
            if ((unsigned)(mdiv0 + dy) >= 48u) continue;    // uniform over the 4 cols
            #pragma unroll
            for (int dx = -1; dx <= 1; ++dx) {
                if ((unsigned)(lx + dx) >= 48u) continue;
                int s = dy * 48 + dx;
                f32x4u v = *(const f32x4u*)(Gb + (size_t)(l + s) * L + s + m0);
                bool e0 = (unsigned)(mmod0 + dx) < 48u;     // only j=0,dx=-1 can fail
                bool e3 = (unsigned)(mmod0 + 3 + dx) < 48u; // only j=3,dx=+1 can fail
                a0 += e0 ? v[0] : 0.f;
                a1 += v[1];
                a2 += v[2];
                a3 += e3 ? v[3] : 0.f;
            }
        }
        float rk = rnK[b * L + l];
        f32x4 o = { a0 * rk * rqv0, a1 * rk * rqv1, a2 * rk * rqv2, a3 * rk * rqv3 };
        *(f32x4*)(R + (size_t)b * L * L + (size_t)l * L + m0) = o;  // cached: re-read by argmax/top3
    }
}

// ---------------- segmented argmax over l (ties -> lowest l) ----------------
__global__ void argmax_part(const float* __restrict__ R, float* __restrict__ pv, int* __restrict__ pi) {
    int m = blockIdx.x * 256 + threadIdx.x;
    int seg = blockIdx.y, b = blockIdx.z;
    const float* Rb = R + (size_t)b * L * L;
    float bv = -3.4e38f; int bi = 0;
    int l0 = seg * SEG;
    #pragma unroll 4
    for (int j = 0; j < SEG; j++) {
        float v = Rb[(size_t)(l0 + j) * L + m];
        if (v > bv) { bv = v; bi = l0 + j; }
    }
    int o = (b * NSEG + seg) * L + m;
    pv[o] = bv; pi[o] = bi;
}

__global__ void argmax_merge(const float* __restrict__ pv, const int* __restrict__ pi,
                             int* __restrict__ hidx) {
    int m = blockIdx.x * 256 + threadIdx.x;
    int b = blockIdx.y;
    float bv = -3.4e38f; int bi = 0;
    #pragma unroll
    for (int s = 0; s < NSEG; s++) {
        int o = (b * NSEG + s) * L + m;
        float v = pv[o];
        if (v > bv) { bv = v; bi = pi[o]; }
    }
    hidx[b * L + m] = bi;
}

// ---------------- segmented top-3 of s_l = R[hidx[l], m] ----------------
__global__ void top3_part(const float* __restrict__ R, const int* __restrict__ hidx,
                          float* __restrict__ pv, int* __restrict__ pr) {
    int m = blockIdx.x * 256 + threadIdx.x;
    int seg = blockIdx.y, b = blockIdx.z;
    const float* Rb = R + (size_t)b * L * L;
    __shared__ int hrow_s[SEG];
    if (threadIdx.x < SEG) hrow_s[threadIdx.x] = hidx[b * L + seg * SEG + threadIdx.x];
    __syncthreads();
    float v0 = -3.4e38f, v1 = -3.4e38f, v2 = -3.4e38f;
    int r0 = 0, r1 = 0, r2 = 0;
    #pragma unroll 4
    for (int j = 0; j < SEG; j++) {
        int row = hrow_s[j];
        float v = Rb[(size_t)row * L + m];
        if (v > v0)      { v2 = v1; r2 = r1; v1 = v0; r1 = r0; v0 = v; r0 = row; }
        else if (v > v1) { v2 = v1; r2 = r1; v1 = v;  r1 = row; }
        else if (v > v2) { v2 = v;  r2 = row; }
    }
    size_t o = ((size_t)(b * NSEG + seg) * 3) * L + m;
    pv[o] = v0; pv[o + L] = v1; pv[o + 2 * L] = v2;
    pr[o] = r0; pr[o + L] = r1; pr[o + 2 * L] = r2;
}

__global__ void top3_merge(const float* __restrict__ pv, const int* __restrict__ pr,
                           float* __restrict__ outS, int* __restrict__ effp) {
    int m = blockIdx.x * 256 + threadIdx.x;
    int b = blockIdx.y;
    float v0 = -3.4e38f, v1 = -3.4e38f, v2 = -3.4e38f;
    int r0 = 0, r1 = 0, r2 = 0;
    for (int s = 0; s < NSEG; s++) {
        size_t o = ((size_t)(b * NSEG + s) * 3) * L + m;
        #pragma unroll
        for (int j = 0; j < 3; j++) {
            float v = pv[o + (size_t)j * L];
            int r = pr[o + (size_t)j * L];
            if (v > v0)      { v2 = v1; r2 = r1; v1 = v0; r1 = r0; v0 = v; r0 = r; }
            else if (v > v1) { v2 = v1; r2 = r1; v1 = v;  r1 = r; }
            else if (v > v2) { v2 = v;  r2 = r; }
        }
    }
    outS[(0 * BATCH + b) * L + m] = v0;
    outS[(1 * BATCH + b) * L + m] = v1;
    outS[(2 * BATCH + b) * L + m] = v2;
    effp[(b * 3 + 0) * L + m] = ((r0 / 48) << 8) | (r0 % 48);
    effp[(b * 3 + 1) * L + m] = ((r1 / 48) << 8) | (r1 % 48);
    effp[(b * 3 + 2) * L + m] = ((r2 / 48) << 8) | (r2 % 48);
}

// ---------------- folds on patch-major sources ----------------
// T1: thread = one 4x4 output quad; 9 x 64B line-aligned patch gathers.
__global__ __launch_bounds__(256) void fold_t1p(const float* __restrict__ refp, const int* __restrict__ effp,
                                                float* __restrict__ outT) {
    const int W = 192;
    int blk = blockIdx.x;                 // 3456 = 8 xcd * 9 tiles * 48 rr
    int xcd = blk & 7;
    int r = blk >> 3;
    int tile = r % 9;
    int rr = r / 9;                       // 0..47
    int i = rr % 3;
    int pw = rr / 3;                      // 0..15
    int plane = xcd + 8 * pw;             // 0..127
    int b = plane >> 6, c = plane & 63;
    int qid = tile * 256 + threadIdx.x;   // 0..2303
    int qy = qid / 48, qx = qid % 48;
    const int* e = effp + (b * 3 + i) * L;
    const float* src = refp + (size_t)plane * (2304 * 16);
    f32x4 acc0 = (f32x4)(0.f), acc1 = (f32x4)(0.f), acc2 = (f32x4)(0.f), acc3 = (f32x4)(0.f);
    #pragma unroll
    for (int dh = -1; dh <= 1; ++dh) {
        int ho = qy + dh;
        if ((unsigned)ho >= 48u) continue;
        #pragma unroll
        for (int dw = -1; dw <= 1; ++dw) {
            int wo = qx + dw;
            if ((unsigned)wo >= 48u) continue;
            int ep = e[ho * 48 + wo];
            int yq = (ep >> 8) - dh, xq = (ep & 255) - dw;
            if ((unsigned)yq >= 48u || (unsigned)xq >= 48u) continue;
            const float* P = src + (size_t)(yq * 48 + xq) * 16;
            acc0 += *(const f32x4*)(P);
            acc1 += *(const f32x4*)(P + 4);
            acc2 += *(const f32x4*)(P + 8);
            acc3 += *(const f32x4*)(P + 12);
        }
    }
    const float k = 1.0f / 9.0f;
    float* dst = outT + (((size_t)i * BATCH + b) * C1 + c) * (size_t)(W * W) + (qy * 4) * W + qx * 4;
    nts4(dst + 0 * W, acc0[0] * k, acc0[1] * k, acc0[2] * k, acc0[3] * k);
    nts4(dst + 1 * W, acc1[0] * k, acc1[1] * k, acc1[2] * k, acc1[3] * k);
    nts4(dst + 2 * W, acc2[0] * k, acc2[1] * k, acc2[2] * k, acc2[3] * k);
    nts4(dst + 3 * W, acc3[0] * k, acc3[1] * k, acc3[2] * k, acc3[3] * k);
}

// T2: thread = one 2x2 output quad; 9 x 16B patch gathers.
__global__ __launch_bounds__(256) void fold_t2p(const float* __restrict__ refp, const int* __restrict__ effp,
                                                float* __restrict__ outT) {
    const int W = 96;
    int blk = blockIdx.x;                 // 6912 = 8 xcd * 9 tiles * 96 rr
    int xcd = blk & 7;
    int r = blk >> 3;
    int tile = r % 9;
    int rr = r / 9;                       // 0..95
    int i = rr % 3;
    int pw = rr / 3;                      // 0..31
    int plane = xcd + 8 * pw;             // 0..255
    int b = plane >> 7, c = plane & 127;
    int qid = tile * 256 + threadIdx.x;   // 0..2303
    int qy = qid / 48, qx = qid % 48;
    const int* e = effp + (b * 3 + i) * L;
    const float* src = refp + (size_t)plane * (2304 * 4);
    f32x4 acc = (f32x4)(0.f);
    #pragma unroll
    for (int dh = -1; dh <= 1; ++dh) {
        int ho = qy + dh;
        if ((unsigned)ho >= 48u) continue;
        #pragma unroll
        for (int dw = -1; dw <= 1; ++dw) {
            int wo = qx + dw;
            if ((unsigned)wo >= 48u) continue;
            int ep = e[ho * 48 + wo];
            int yq = (ep >> 8) - dh, xq = (ep & 255) - dw;
            if ((unsigned)yq >= 48u || (unsigned)xq >= 48u) continue;
            acc += *(const f32x4*)(src + (size_t)(yq * 48 + xq) * 4);
        }
    }
    const float k = 1.0f / 9.0f;
    float* dst = outT + (((size_t)i * BATCH + b) * C2 + c) * (size_t)(W * W) + (qy * 2) * W + qx * 2;
    nts2(dst,     acc[0] * k, acc[1] * k);
    nts2(dst + W, acc[2] * k, acc[3] * k);
}

// T3: unchanged (48x48 planes are L1-resident).
__global__ __launch_bounds__(192) void fold_t3(const float* __restrict__ ref, const int* __restrict__ effp,
                                               float* __restrict__ outT) {
    const int W = 48;
    int blk = blockIdx.x;
    int xcd = blk & 7;
    int r = blk >> 3;
    int tile = r % 3;
    int rr = r / 3;
    int i = rr % 3;
    int pw = rr / 3;                  // 0..63
    int plane = xcd + 8 * pw;         // 0..511
    int b = plane >> 8, c = plane & 255;
    int id = tile * 192 + threadIdx.x;     // y*12 + xq in [0, 576)
    int y = id / 12, x0 = (id % 12) * 4;
    const int* e = effp + (b * 3 + i) * L;
    const float* src = ref + ((size_t)b * C3 + c) * (W * W);
    float s[4] = {0.f, 0.f, 0.f, 0.f};
    #pragma unroll
    for (int dh = -1; dh <= 1; ++dh) {
        int ho = y + dh;
        if ((unsigned)ho >= 48u) continue;
        int ep6[6];
        #pragma unroll
        for (int j = 0; j < 6; ++j) {
            int wo = x0 - 1 + j;
            ep6[j] = ((unsigned)wo < 48u) ? e[ho * 48 + wo] : -1;
        }
        #pragma unroll
        for (int xi = 0; xi < 4; ++xi) {
            #pragma unroll
            for (int dw = -1; dw <= 1; ++dw) {
                int ep = ep6[xi + dw + 1];
                if (ep < 0) continue;
                int yy = (ep >> 8) - dh, xx = (ep & 255) - dw;
                if ((unsigned)yy >= 48u || (unsigned)xx >= 48u) continue;
                s[xi] += src[yy * W + xx];
            }
        }
    }
    const float k = 1.0f / 9.0f;
    nts4(outT + (((size_t)i * BATCH + b) * C3 + c) * (size_t)(W * W) + y * W + x0,
         s[0] * k, s[1] * k, s[2] * k, s[3] * k);
}

extern "C" void kernel_launch(void* const* d_in, const int* in_sizes, int n_in,
                              void* d_out, int out_size, void* d_ws, size_t ws_size,
                              hipStream_t stream) {
    const float* lr    = (const float*)d_in[0];
    const float* refsr = (const float*)d_in[1];
    const float* ref1  = (const float*)d_in[2];
    const float* ref2  = (const float*)d_in[3];
    const float* ref3  = (const float*)d_in[4];
    float* out = (float*)d_out;

    float*  R   = (float*)d_ws;                              // B*L*L fp32
    float*  G   = R + (size_t)BATCH * L * L;                 // B*L*L fp32
    __bf16* Khi = (__bf16*)(G + (size_t)BATCH * L * L);      // B*L*GK bf16 each
    __bf16* Klo = Khi + (size_t)BATCH * L * GK;
    __bf16* Qhi = Klo + (size_t)BATCH * L * GK;
    __bf16* Qlo = Qhi + (size_t)BATCH * L * GK;
    float* ssQ = (float*)(Qlo + (size_t)BATCH * L * GK);
    float* ssK = ssQ + BATCH * L;
    float* rnQ = ssK + BATCH * L;
    float* rnK = rnQ + BATCH * L;
    float* apv = rnK + BATCH * L;
    float* pv  = apv + BATCH * NSEG * L;
    int*   api = (int*)(pv + (size_t)BATCH * NSEG * 3 * L);
    int*   pr  = api + BATCH * NSEG * L;
    int*   hidx = pr + (size_t)BATCH * NSEG * 3 * L;
    int*   effp = hidx + BATCH * L;
    float* ref1p = (float*)(effp + BATCH * 3 * L);           // 2*64*2304*16 fp32 (18.9 MB)
    float* ref2p = ref1p + (size_t)BATCH * C1 * 2304 * 16;   // 2*128*2304*4 fp32 (9.4 MB)

    ssq_kernel<<<dim3(18, 2), 256, 0, stream>>>(lr, refsr, ssQ, ssK);
    norm_kernel<<<dim3(18, 2), 256, 0, stream>>>(ssQ, ssK, rnQ, rnK);
    split_t<<<dim3(36, 4, BATCH * 2), 256, 0, stream>>>(lr, refsr, Qhi, Qlo, Khi, Klo);
    t1prep<<<1152, 256, 0, stream>>>(ref1, ref1p);
    t2prep<<<2304, 256, 0, stream>>>(ref2, ref2p);

    gemm_g<<<dim3(18, 36, BATCH), 256, 0, stream>>>(Khi, Klo, Qhi, Qlo, G);
    stencil_R<<<1152, 576, 0, stream>>>(G, rnK, rnQ, R);

    argmax_part<<<dim3(9, NSEG, BATCH), 256, 0, stream>>>(R, apv, api);
    argmax_merge<<<dim3(9, BATCH), 256, 0, stream>>>(apv, api, hidx);
    top3_part<<<dim3(9, NSEG, BATCH), 256, 0, stream>>>(R, hidx, pv, pr);
    top3_merge<<<dim3(9, BATCH), 256, 0, stream>>>(pv, pr, out, effp);

    fold_t3<<<4608,  192, 0, stream>>>(ref3, effp, out + OFF_T3);
    fold_t2p<<<6912, 256, 0, stream>>>(ref2p, effp, out + OFF_T2);
    fold_t1p<<<3456, 256, 0, stream>>>(ref1p, effp, out + OFF_T1);
}

// Round 4
// 441.499 us; speedup vs baseline: 1.7334x; 1.1008x over previous
//
#include <hip/hip_runtime.h>
#include <math.h>

// Problem constants
#define BATCH 2
#define C3 256
#define C2 128
#define C1 64
#define HH 48
#define WW 48
#define L 2304          // 48*48 unfold positions
#define GK 256          // channel dim for G-GEMM
#define BK2 64          // K-tile (bf16) for G-GEMM
#define NSEG 16
#define SEG 144         // 2304/16

// Output flat offsets (float elements)
#define OFF_T3 13824
#define OFF_T2 3552768
#define OFF_T1 10630656

typedef __bf16 bf16x8 __attribute__((ext_vector_type(8)));
typedef float  f32x4  __attribute__((ext_vector_type(4)));
typedef float  f32x2  __attribute__((ext_vector_type(2)));
typedef int    i32x4  __attribute__((ext_vector_type(4)));
// dword-aligned (not 16B) float4 for shifted stencil loads
typedef float  f32x4u __attribute__((ext_vector_type(4), aligned(4)));

__device__ __forceinline__ void gload16(const void* g, void* l) {
    __builtin_amdgcn_global_load_lds(
        (const __attribute__((address_space(1))) void*)g,
        (__attribute__((address_space(3))) void*)l, 16, 0, 0);
}

__device__ __forceinline__ void nts4(float* p, float a, float b, float c, float d) {
    f32x4 v = {a, b, c, d};
    __builtin_nontemporal_store(v, (f32x4*)p);
}
__device__ __forceinline__ void nts2(float* p, float a, float b) {
    f32x2 v = {a, b};
    __builtin_nontemporal_store(v, (f32x2*)p);
}

// ---------------- per-pixel channel sum of squares (both images) ----------------
__global__ void ssq_kernel(const float* __restrict__ lr, const float* __restrict__ refsr,
                           float* __restrict__ ssQ, float* __restrict__ ssK) {
    int idx = blockIdx.x * 256 + threadIdx.x;
    if (idx >= BATCH * L) return;
    const float* img = blockIdx.y ? refsr : lr;
    float* ss = blockIdx.y ? ssK : ssQ;
    int b = idx / L, yx = idx % L;
    const float* p = img + (size_t)b * C3 * L + yx;
    float s = 0.f;
    #pragma unroll 4
    for (int c = 0; c < C3; ++c) { float v = p[(size_t)c * L]; s += v * v; }
    ss[idx] = s;
}

// ---------------- 3x3 window sum -> 1/max(sqrt, eps) (both) ----------------
__global__ void norm_kernel(const float* __restrict__ ssQ, const float* __restrict__ ssK,
                            float* __restrict__ rnQ, float* __restrict__ rnK) {
    int idx = blockIdx.x * 256 + threadIdx.x;
    if (idx >= BATCH * L) return;
    const float* ss = blockIdx.y ? ssK : ssQ;
    float* rn = blockIdx.y ? rnK : rnQ;
    int b = idx / L, l = idx % L;
    int ly = l / WW, lx = l % WW;
    const float* s = ss + b * L;
    float acc = 0.f;
    #pragma unroll
    for (int dy = -1; dy <= 1; ++dy) {
        int yy = ly + dy;
        if ((unsigned)yy >= (unsigned)HH) continue;
        #pragma unroll
        for (int dx = -1; dx <= 1; ++dx) {
            int xx = lx + dx;
            if ((unsigned)xx >= (unsigned)WW) continue;
            acc += s[yy * WW + xx];
        }
    }
    float n = sqrtf(acc);
    n = fmaxf(n, 1e-12f);
    rn[idx] = 1.0f / n;
}

// ---------------- transpose [C][pix] -> [pix][C] + bf16 hi/lo split (both images) ----
__global__ __launch_bounds__(256) void split_t(const float* __restrict__ lr,
                                               const float* __restrict__ refsr,
                                               __bf16* __restrict__ Qhi, __bf16* __restrict__ Qlo,
                                               __bf16* __restrict__ Khi, __bf16* __restrict__ Klo) {
    __shared__ float tile[64][65];
    int bz = blockIdx.z;
    int b = bz >> 1;
    const float* img = (bz & 1) ? refsr : lr;
    __bf16* dh = (bz & 1) ? Khi : Qhi;
    __bf16* dl = (bz & 1) ? Klo : Qlo;
    int u0 = blockIdx.x * 64, c0 = blockIdx.y * 64;
    int t = threadIdx.x;
    {
        int ul = t & 63, cl0 = t >> 6;
        const float* src = img + ((size_t)b * C3 + c0) * L + u0;
        #pragma unroll
        for (int r = 0; r < 16; ++r) {
            int cl = cl0 + r * 4;
            tile[cl][ul] = src[(size_t)cl * L + ul];
        }
    }
    __syncthreads();
    {
        int cl = t & 63, ul0 = t >> 6;
        __bf16* oh = dh + ((size_t)b * L + u0) * GK + c0 + cl;
        __bf16* ol = dl + ((size_t)b * L + u0) * GK + c0 + cl;
        #pragma unroll
        for (int r = 0; r < 16; ++r) {
            int ul = ul0 + r * 4;
            float v = tile[cl][ul];
            __bf16 h = (__bf16)v;
            float lo = v - (float)h;
            oh[(size_t)ul * GK] = h;
            ol[(size_t)ul * GK] = (__bf16)lo;
        }
    }
}

// ---------------- patch-major re-layouts for the fold gather sources ----------------
// ref1 [b][c][192][192] -> ref1p [(b*64+c)*2304 + qy*48+qx][4][4]  (64B/patch, line-aligned)
__global__ __launch_bounds__(256) void t1prep(const float* __restrict__ ref, float* __restrict__ refp) {
    int id = blockIdx.x * 256 + threadIdx.x;     // 294912 patches
    int qx = id % 48, t = id / 48;
    int qy = t % 48, pc = t / 48;                // pc = b*64+c
    const float* src = ref + (size_t)pc * (192 * 192) + (qy * 4) * 192 + qx * 4;
    float* dst = refp + (size_t)id * 16;
    #pragma unroll
    for (int r = 0; r < 4; ++r) {
        f32x4 v = *(const f32x4*)(src + r * 192);
        *(f32x4*)(dst + r * 4) = v;
    }
}

// ref2 [b][c][96][96] -> ref2p [(b*128+c)*2304 + qy*48+qx][2][2]  (16B/patch)
__global__ __launch_bounds__(256) void t2prep(const float* __restrict__ ref, float* __restrict__ refp) {
    int id = blockIdx.x * 256 + threadIdx.x;     // 589824 patches
    int qx = id % 48, t = id / 48;
    int qy = t % 48, pc = t / 48;                // pc = b*128+c
    const float* src = ref + (size_t)pc * (96 * 96) + (qy * 2) * 96 + qx * 2;
    f32x2 a = *(const f32x2*)(src);
    f32x2 b2 = *(const f32x2*)(src + 96);
    f32x4 v = { a[0], a[1], b2[0], b2[1] };
    *(f32x4*)(refp + (size_t)id * 4) = v;
}

// ---------------- split-bf16 MFMA GEMM NT over K=256: G[u,v] ----------------
__global__ __launch_bounds__(256) void gemm_g(const __bf16* __restrict__ Khi,
                                              const __bf16* __restrict__ Klo,
                                              const __bf16* __restrict__ Qhi,
                                              const __bf16* __restrict__ Qlo,
                                              float* __restrict__ Gg) {
    __shared__ __align__(16) __bf16 Ah[64 * BK2];
    __shared__ __align__(16) __bf16 Al[64 * BK2];
    __shared__ __align__(16) __bf16 Bh[128 * BK2];
    __shared__ __align__(16) __bf16 Bl[128 * BK2];
    int t = threadIdx.x;
    int lane = t & 63;
    int wv = t >> 6;
    int b = blockIdx.z;
    size_t ioff = (size_t)b * L * GK;
    const __bf16* Ahg = Khi + ioff;   // rows u (refsr)
    const __bf16* Alg = Klo + ioff;
    const __bf16* Bhg = Qhi + ioff;   // rows v (lr)
    const __bf16* Blg = Qlo + ioff;
    int m0 = blockIdx.x * 128;
    int l0 = blockIdx.y * 64;
    int wl = wv >> 1, wm = wv & 1;    // wave tile: 32(u) x 64(v)
    int q = lane >> 4, r16 = lane & 15;

    f32x4 acc[2][4];
    #pragma unroll
    for (int i = 0; i < 2; i++)
        #pragma unroll
        for (int j = 0; j < 4; j++) acc[i][j] = (f32x4)(0.f);

    for (int k0 = 0; k0 < GK; k0 += BK2) {
        #pragma unroll
        for (int hh = 0; hh < 2; ++hh) {          // A: 512 chunks of 16B
            int c = t + hh * 256;
            int row = c >> 3, qo = c & 7;
            size_t ga = (size_t)(l0 + row) * GK + k0 + ((qo ^ (row & 7)) * 8);
            gload16(Ahg + ga, &Ah[c * 8]);
            gload16(Alg + ga, &Al[c * 8]);
        }
        #pragma unroll
        for (int hh = 0; hh < 4; ++hh) {          // B: 1024 chunks
            int c = t + hh * 256;
            int row = c >> 3, qo = c & 7;
            size_t gb = (size_t)(m0 + row) * GK + k0 + ((qo ^ (row & 7)) * 8);
            gload16(Bhg + gb, &Bh[c * 8]);
            gload16(Blg + gb, &Bl[c * 8]);
        }
        __syncthreads();

        #pragma unroll
        for (int h = 0; h < 2; ++h) {             // two k-32 halves of BK=64
            bf16x8 ah[2], al[2], bh[4], bl[4];
            #pragma unroll
            for (int i = 0; i < 2; ++i) {
                int row = wl * 32 + i * 16 + r16;
                int ch = (h * 4 + q) ^ (row & 7);
                ah[i] = *(const bf16x8*)&Ah[row * BK2 + ch * 8];
                al[i] = *(const bf16x8*)&Al[row * BK2 + ch * 8];
            }
            #pragma unroll
            for (int j = 0; j < 4; ++j) {
                int row = wm * 64 + j * 16 + r16;
                int ch = (h * 4 + q) ^ (row & 7);
                bh[j] = *(const bf16x8*)&Bh[row * BK2 + ch * 8];
                bl[j] = *(const bf16x8*)&Bl[row * BK2 + ch * 8];
            }
            #pragma unroll
            for (int i = 0; i < 2; ++i)
                #pragma unroll
                for (int j = 0; j < 4; ++j) {
                    acc[i][j] = __builtin_amdgcn_mfma_f32_16x16x32_bf16(ah[i], bh[j], acc[i][j], 0, 0, 0);
                    acc[i][j] = __builtin_amdgcn_mfma_f32_16x16x32_bf16(ah[i], bl[j], acc[i][j], 0, 0, 0);
                    acc[i][j] = __builtin_amdgcn_mfma_f32_16x16x32_bf16(al[i], bh[j], acc[i][j], 0, 0, 0);
                }
        }
        __syncthreads();
    }

    float* Cb = Gg + (size_t)b * L * L;
    #pragma unroll
    for (int i = 0; i < 2; ++i) {
        int rowb = l0 + wl * 32 + i * 16 + q * 4;
        #pragma unroll
        for (int j = 0; j < 4; ++j) {
            int col = m0 + wm * 64 + j * 16 + r16;
            #pragma unroll
            for (int r = 0; r < 4; ++r)
                Cb[(size_t)(rowb + r) * L + col] = acc[i][j][r];
        }
    }
}

// ---------------- R[l,m] = rnK[l]*rnQ[m]*sum_{9 diag shifts} G[l+s, m+s] ----------------
__global__ __launch_bounds__(576) void stencil_R(const float* __restrict__ G,
                                                 const float* __restrict__ rnK,
                                                 const float* __restrict__ rnQ,
                                                 float* __restrict__ R) {
    int blk = blockIdx.x;                 // 0..1151
    int xcd = blk & 7, idx = blk >> 3;    // 144 chunks per XCD
    int gc = xcd * 144 + idx;             // contiguous l-chunks per XCD
    int b = gc / 576;
    int lbase = (gc % 576) * 4;
    int m0 = threadIdx.x * 4;
    const float* Gb = G + (size_t)b * L * L;
    int mdiv0 = m0 / 48, mmod0 = m0 % 48; // 4 cols never straddle a 48-boundary
    const float* rq = rnQ + b * L + m0;
    float rqv0 = rq[0], rqv1 = rq[1], rqv2 = rq[2], rqv3 = rq[3];

    #pragma unroll
    for (int li = 0; li < 4; ++li) {
        int l = lbase + li;
        int ly = l / 48, lx = l % 48;
        float a0 = 0.f, a1 = 0.f, a2 = 0.f, a3 = 0.f;
        #pragma unroll
        for (int dy = -1; dy <= 1; ++dy) {
            if ((unsigned)(ly + dy) >= 48u) continue;
            if ((unsigned)(mdiv0 + dy) >= 48u) continue;    // uniform over the 4 cols
            #pragma unroll
            for (int dx = -1; dx <= 1; ++dx) {
                if ((unsigned)(lx + dx) >= 48u) continue;
                int s = dy * 48 + dx;
                f32x4u v = *(const f32x4u*)(Gb + (size_t)(l + s) * L + s + m0);
                bool e0 = (unsigned)(mmod0 + dx) < 48u;     // only j=0,dx=-1 can fail
                bool e3 = (unsigned)(mmod0 + 3 + dx) < 48u; // only j=3,dx=+1 can fail
                a0 += e0 ? v[0] : 0.f;
                a1 += v[1];
                a2 += v[2];
                a3 += e3 ? v[3] : 0.f;
            }
        }
        float rk = rnK[b * L + l];
        f32x4 o = { a0 * rk * rqv0, a1 * rk * rqv1, a2 * rk * rqv2, a3 * rk * rqv3 };
        *(f32x4*)(R + (size_t)b * L * L + (size_t)l * L + m0) = o;  // cached: re-read by argmax/top3
    }
}

// ---------------- segmented argmax over l (ties -> lowest l) ----------------
__global__ void argmax_part(const float* __restrict__ R, float* __restrict__ pv, int* __restrict__ pi) {
    int m = blockIdx.x * 256 + threadIdx.x;
    int seg = blockIdx.y, b = blockIdx.z;
    const float* Rb = R + (size_t)b * L * L;
    float bv = -3.4e38f; int bi = 0;
    int l0 = seg * SEG;
    #pragma unroll 4
    for (int j = 0; j < SEG; j++) {
        float v = Rb[(size_t)(l0 + j) * L + m];
        if (v > bv) { bv = v; bi = l0 + j; }
    }
    int o = (b * NSEG + seg) * L + m;
    pv[o] = bv; pi[o] = bi;
}

__global__ void argmax_merge(const float* __restrict__ pv, const int* __restrict__ pi,
                             int* __restrict__ hidx) {
    int m = blockIdx.x * 256 + threadIdx.x;
    int b = blockIdx.y;
    float bv = -3.4e38f; int bi = 0;
    #pragma unroll
    for (int s = 0; s < NSEG; s++) {
        int o = (b * NSEG + s) * L + m;
        float v = pv[o];
        if (v > bv) { bv = v; bi = pi[o]; }
    }
    hidx[b * L + m] = bi;
}

// ---------------- segmented top-3 of s_l = R[hidx[l], m] ----------------
__global__ void top3_part(const float* __restrict__ R, const int* __restrict__ hidx,
                          float* __restrict__ pv, int* __restrict__ pr) {
    int m = blockIdx.x * 256 + threadIdx.x;
    int seg = blockIdx.y, b = blockIdx.z;
    const float* Rb = R + (size_t)b * L * L;
    __shared__ int hrow_s[SEG];
    if (threadIdx.x < SEG) hrow_s[threadIdx.x] = hidx[b * L + seg * SEG + threadIdx.x];
    __syncthreads();
    float v0 = -3.4e38f, v1 = -3.4e38f, v2 = -3.4e38f;
    int r0 = 0, r1 = 0, r2 = 0;
    #pragma unroll 4
    for (int j = 0; j < SEG; j++) {
        int row = hrow_s[j];
        float v = Rb[(size_t)row * L + m];
        if (v > v0)      { v2 = v1; r2 = r1; v1 = v0; r1 = r0; v0 = v; r0 = row; }
        else if (v > v1) { v2 = v1; r2 = r1; v1 = v;  r1 = row; }
        else if (v > v2) { v2 = v;  r2 = row; }
    }
    size_t o = ((size_t)(b * NSEG + seg) * 3) * L + m;
    pv[o] = v0; pv[o + L] = v1; pv[o + 2 * L] = v2;
    pr[o] = r0; pr[o + L] = r1; pr[o + 2 * L] = r2;
}

__global__ void top3_merge(const float* __restrict__ pv, const int* __restrict__ pr,
                           float* __restrict__ outS, int* __restrict__ effp) {
    int m = blockIdx.x * 256 + threadIdx.x;
    int b = blockIdx.y;
    float v0 = -3.4e38f, v1 = -3.4e38f, v2 = -3.4e38f;
    int r0 = 0, r1 = 0, r2 = 0;
    for (int s = 0; s < NSEG; s++) {
        size_t o = ((size_t)(b * NSEG + s) * 3) * L + m;
        #pragma unroll
        for (int j = 0; j < 3; j++) {
            float v = pv[o + (size_t)j * L];
            int r = pr[o + (size_t)j * L];
            if (v > v0)      { v2 = v1; r2 = r1; v1 = v0; r1 = r0; v0 = v; r0 = r; }
            else if (v > v1) { v2 = v1; r2 = r1; v1 = v;  r1 = r; }
            else if (v > v2) { v2 = v;  r2 = r; }
        }
    }
    outS[(0 * BATCH + b) * L + m] = v0;
    outS[(1 * BATCH + b) * L + m] = v1;
    outS[(2 * BATCH + b) * L + m] = v2;
    effp[(b * 3 + 0) * L + m] = ((r0 / 48) << 8) | (r0 % 48);
    effp[(b * 3 + 1) * L + m] = ((r1 / 48) << 8) | (r1 % 48);
    effp[(b * 3 + 2) * L + m] = ((r2 / 48) << 8) | (r2 % 48);
}

// ---------------- folds on patch-major sources ----------------
// T1: thread = one 4x4 output quad; 9 x 64B line-aligned patch gathers.
__global__ __launch_bounds__(256) void fold_t1p(const float* __restrict__ refp, const int* __restrict__ effp,
                                                float* __restrict__ outT) {
    const int W = 192;
    int blk = blockIdx.x;                 // 3456 = 8 xcd * 9 tiles * 48 rr
    int xcd = blk & 7;
    int r = blk >> 3;
    int tile = r % 9;
    int rr = r / 9;                       // 0..47
    int i = rr % 3;
    int pw = rr / 3;                      // 0..15
    int plane = xcd + 8 * pw;             // 0..127
    int b = plane >> 6, c = plane & 63;
    int qid = tile * 256 + threadIdx.x;   // 0..2303
    int qy = qid / 48, qx = qid % 48;
    const int* e = effp + (b * 3 + i) * L;
    const float* src = refp + (size_t)plane * (2304 * 16);
    f32x4 acc0 = (f32x4)(0.f), acc1 = (f32x4)(0.f), acc2 = (f32x4)(0.f), acc3 = (f32x4)(0.f);
    #pragma unroll
    for (int dh = -1; dh <= 1; ++dh) {
        int ho = qy + dh;
        if ((unsigned)ho >= 48u) continue;
        #pragma unroll
        for (int dw = -1; dw <= 1; ++dw) {
            int wo = qx + dw;
            if ((unsigned)wo >= 48u) continue;
            int ep = e[ho * 48 + wo];
            int yq = (ep >> 8) - dh, xq = (ep & 255) - dw;
            if ((unsigned)yq >= 48u || (unsigned)xq >= 48u) continue;
            const float* P = src + (size_t)(yq * 48 + xq) * 16;
            acc0 += *(const f32x4*)(P);
            acc1 += *(const f32x4*)(P + 4);
            acc2 += *(const f32x4*)(P + 8);
            acc3 += *(const f32x4*)(P + 12);
        }
    }
    const float k = 1.0f / 9.0f;
    float* dst = outT + (((size_t)i * BATCH + b) * C1 + c) * (size_t)(W * W) + (qy * 4) * W + qx * 4;
    nts4(dst + 0 * W, acc0[0] * k, acc0[1] * k, acc0[2] * k, acc0[3] * k);
    nts4(dst + 1 * W, acc1[0] * k, acc1[1] * k, acc1[2] * k, acc1[3] * k);
    nts4(dst + 2 * W, acc2[0] * k, acc2[1] * k, acc2[2] * k, acc2[3] * k);
    nts4(dst + 3 * W, acc3[0] * k, acc3[1] * k, acc3[2] * k, acc3[3] * k);
}

// T2: thread = one 2x2 output quad; 9 x 16B patch gathers.
__global__ __launch_bounds__(256) void fold_t2p(const float* __restrict__ refp, const int* __restrict__ effp,
                                                float* __restrict__ outT) {
    const int W = 96;
    int blk = blockIdx.x;                 // 6912 = 8 xcd * 9 tiles * 96 rr
    int xcd = blk & 7;
    int r = blk >> 3;
    int tile = r % 9;
    int rr = r / 9;                       // 0..95
    int i = rr % 3;
    int pw = rr / 3;                      // 0..31
    int plane = xcd + 8 * pw;             // 0..255
    int b = plane >> 7, c = plane & 127;
    int qid = tile * 256 + threadIdx.x;   // 0..2303
    int qy = qid / 48, qx = qid % 48;
    const int* e = effp + (b * 3 + i) * L;
    const float* src = refp + (size_t)plane * (2304 * 4);
    f32x4 acc = (f32x4)(0.f);
    #pragma unroll
    for (int dh = -1; dh <= 1; ++dh) {
        int ho = qy + dh;
        if ((unsigned)ho >= 48u) continue;
        #pragma unroll
        for (int dw = -1; dw <= 1; ++dw) {
            int wo = qx + dw;
            if ((unsigned)wo >= 48u) continue;
            int ep = e[ho * 48 + wo];
            int yq = (ep >> 8) - dh, xq = (ep & 255) - dw;
            if ((unsigned)yq >= 48u || (unsigned)xq >= 48u) continue;
            acc += *(const f32x4*)(src + (size_t)(yq * 48 + xq) * 4);
        }
    }
    const float k = 1.0f / 9.0f;
    float* dst = outT + (((size_t)i * BATCH + b) * C2 + c) * (size_t)(W * W) + (qy * 2) * W + qx * 2;
    nts2(dst,     acc[0] * k, acc[1] * k);
    nts2(dst + W, acc[2] * k, acc[3] * k);
}

// T3: LDS-staged gather. Block = one (plane, i): stage the 9KB plane + padded
// ep-table into LDS, then the divergent 3x3 gather runs on ds_read (32 banks,
// ~2 lanes/bank random) instead of L1 tag-walks (~57 cyc/scattered VMEM inst).
__global__ __launch_bounds__(576) void fold_t3_lds(const float* __restrict__ ref, const int* __restrict__ effp,
                                                   float* __restrict__ outT) {
    const int W = 48;
    __shared__ float sP[2304];
    __shared__ int   sE[48 * 49];          // stride 49: rotates banks per row
    int blk = blockIdx.x;                  // 1536 = 8 xcd * 192
    int xcd = blk & 7;
    int gc = xcd * 192 + (blk >> 3);       // contiguous plane-chunks per XCD
    int plane = gc / 3, i = gc % 3;        // plane = b*256 + c
    int b = plane >> 8, c = plane & 255;
    int t = threadIdx.x;

    {   // stage plane (one float4/thread) + ep table (one int4/thread, re-padded)
        const float* src = ref + (size_t)plane * (W * W);
        *(f32x4*)&sP[t * 4] = *(const f32x4*)(src + t * 4);
        const int* e = effp + (b * 3 + i) * L;
        i32x4 ev = *(const i32x4*)(e + t * 4);
        #pragma unroll
        for (int k = 0; k < 4; ++k) {
            int id = t * 4 + k;
            sE[(id / 48) * 49 + (id % 48)] = ev[k];
        }
    }
    __syncthreads();

    int y = t / 12, x0 = (t % 12) * 4;     // 576 threads cover 48x12 quads of 4 px
    float s0 = 0.f, s1 = 0.f, s2 = 0.f, s3 = 0.f;
    #pragma unroll
    for (int dh = -1; dh <= 1; ++dh) {
        int ho = y + dh;
        if ((unsigned)ho >= 48u) continue;
        int ep6[6];
        #pragma unroll
        for (int j = 0; j < 6; ++j) {
            int wo = x0 - 1 + j;
            ep6[j] = ((unsigned)wo < 48u) ? sE[ho * 49 + wo] : -1;
        }
        #pragma unroll
        for (int xi = 0; xi < 4; ++xi) {
            float acc = 0.f;
            #pragma unroll
            for (int dw = -1; dw <= 1; ++dw) {
                int ep = ep6[xi + dw + 1];
                if (ep < 0) continue;
                int yy = (ep >> 8) - dh, xx = (ep & 255) - dw;
                if ((unsigned)yy >= 48u || (unsigned)xx >= 48u) continue;
                acc += sP[yy * W + xx];
            }
            if (xi == 0) s0 += acc; else if (xi == 1) s1 += acc;
            else if (xi == 2) s2 += acc; else s3 += acc;
        }
    }
    const float k = 1.0f / 9.0f;
    nts4(outT + (((size_t)i * BATCH + b) * C3 + c) * (size_t)(W * W) + y * W + x0,
         s0 * k, s1 * k, s2 * k, s3 * k);
}

extern "C" void kernel_launch(void* const* d_in, const int* in_sizes, int n_in,
                              void* d_out, int out_size, void* d_ws, size_t ws_size,
                              hipStream_t stream) {
    const float* lr    = (const float*)d_in[0];
    const float* refsr = (const float*)d_in[1];
    const float* ref1  = (const float*)d_in[2];
    const float* ref2  = (const float*)d_in[3];
    const float* ref3  = (const float*)d_in[4];
    float* out = (float*)d_out;

    float*  R   = (float*)d_ws;                              // B*L*L fp32
    float*  G   = R + (size_t)BATCH * L * L;                 // B*L*L fp32
    __bf16* Khi = (__bf16*)(G + (size_t)BATCH * L * L);      // B*L*GK bf16 each
    __bf16* Klo = Khi + (size_t)BATCH * L * GK;
    __bf16* Qhi = Klo + (size_t)BATCH * L * GK;
    __bf16* Qlo = Qhi + (size_t)BATCH * L * GK;
    float* ssQ = (float*)(Qlo + (size_t)BATCH * L * GK);
    float* ssK = ssQ + BATCH * L;
    float* rnQ = ssK + BATCH * L;
    float* rnK = rnQ + BATCH * L;
    float* apv = rnK + BATCH * L;
    float* pv  = apv + BATCH * NSEG * L;
    int*   api = (int*)(pv + (size_t)BATCH * NSEG * 3 * L);
    int*   pr  = api + BATCH * NSEG * L;
    int*   hidx = pr + (size_t)BATCH * NSEG * 3 * L;
    int*   effp = hidx + BATCH * L;
    float* ref1p = (float*)(effp + BATCH * 3 * L);           // 2*64*2304*16 fp32 (18.9 MB)
    float* ref2p = ref1p + (size_t)BATCH * C1 * 2304 * 16;   // 2*128*2304*4 fp32 (9.4 MB)

    ssq_kernel<<<dim3(18, 2), 256, 0, stream>>>(lr, refsr, ssQ, ssK);
    norm_kernel<<<dim3(18, 2), 256, 0, stream>>>(ssQ, ssK, rnQ, rnK);
    split_t<<<dim3(36, 4, BATCH * 2), 256, 0, stream>>>(lr, refsr, Qhi, Qlo, Khi, Klo);
    t1prep<<<1152, 256, 0, stream>>>(ref1, ref1p);
    t2prep<<<2304, 256, 0, stream>>>(ref2, ref2p);

    gemm_g<<<dim3(18, 36, BATCH), 256, 0, stream>>>(Khi, Klo, Qhi, Qlo, G);
    stencil_R<<<1152, 576, 0, stream>>>(G, rnK, rnQ, R);

    argmax_part<<<dim3(9, NSEG, BATCH), 256, 0, stream>>>(R, apv, api);
    argmax_merge<<<dim3(9, BATCH), 256, 0, stream>>>(apv, api, hidx);
    top3_part<<<dim3(9, NSEG, BATCH), 256, 0, stream>>>(R, hidx, pv, pr);
    top3_merge<<<dim3(9, BATCH), 256, 0, stream>>>(pv, pr, out, effp);

    fold_t3_lds<<<1536, 576, 0, stream>>>(ref3, effp, out + OFF_T3);
    fold_t2p<<<6912, 256, 0, stream>>>(ref2p, effp, out + OFF_T2);
    fold_t1p<<<3456, 256, 0, stream>>>(ref1p, effp, out + OFF_T1);
}

// Round 5
// 388.221 us; speedup vs baseline: 1.9713x; 1.1372x over previous
//
#include <hip/hip_runtime.h>
#include <math.h>

// Problem constants
#define BATCH 2
#define C3 256
#define C2 128
#define C1 64
#define HH 48
#define WW 48
#define L 2304          // 48*48 unfold positions
#define GK 256          // channel dim for G-GEMM
#define BK2 64          // K-tile (bf16) for G-GEMM
#define NSEG 16
#define SEG 144         // 2304/16

// Output flat offsets (float elements)
#define OFF_T3 13824
#define OFF_T2 3552768
#define OFF_T1 10630656

typedef __bf16 bf16x8 __attribute__((ext_vector_type(8)));
typedef float  f32x4  __attribute__((ext_vector_type(4)));
typedef float  f32x2  __attribute__((ext_vector_type(2)));
typedef int    i32x4  __attribute__((ext_vector_type(4)));
// dword-aligned (not 16B) float4 for shifted stencil loads
typedef float  f32x4u __attribute__((ext_vector_type(4), aligned(4)));

__device__ __forceinline__ void gload16(const void* g, void* l) {
    __builtin_amdgcn_global_load_lds(
        (const __attribute__((address_space(1))) void*)g,
        (__attribute__((address_space(3))) void*)l, 16, 0, 0);
}

__device__ __forceinline__ void nts4(float* p, float a, float b, float c, float d) {
    f32x4 v = {a, b, c, d};
    __builtin_nontemporal_store(v, (f32x4*)p);
}
__device__ __forceinline__ void nts2(float* p, float a, float b) {
    f32x2 v = {a, b};
    __builtin_nontemporal_store(v, (f32x2*)p);
}

// ---------------- per-pixel channel sum of squares, 4-way channel split ----------------
// grid (18, 8): y = img + 2*seg; each thread sums 64 channels -> ss4[seg][b][L]
__global__ void ssq_kernel(const float* __restrict__ lr, const float* __restrict__ refsr,
                           float* __restrict__ ssQ4, float* __restrict__ ssK4) {
    int idx = blockIdx.x * 256 + threadIdx.x;
    if (idx >= BATCH * L) return;
    int img_i = blockIdx.y & 1, seg = blockIdx.y >> 1;
    const float* img = img_i ? refsr : lr;
    float* ss = (img_i ? ssK4 : ssQ4) + seg * (BATCH * L);
    int b = idx / L, yx = idx % L;
    const float* p = img + ((size_t)b * C3 + seg * 64) * L + yx;
    float s = 0.f;
    #pragma unroll 4
    for (int c = 0; c < 64; ++c) { float v = p[(size_t)c * L]; s += v * v; }
    ss[idx] = s;
}

// ---------------- 3x3 window sum over 4 partials -> 1/max(sqrt, eps) (both) ----------------
__global__ void norm_kernel(const float* __restrict__ ssQ4, const float* __restrict__ ssK4,
                            float* __restrict__ rnQ, float* __restrict__ rnK) {
    int idx = blockIdx.x * 256 + threadIdx.x;
    if (idx >= BATCH * L) return;
    const float* ss = blockIdx.y ? ssK4 : ssQ4;
    float* rn = blockIdx.y ? rnK : rnQ;
    int b = idx / L, l = idx % L;
    int ly = l / WW, lx = l % WW;
    const float* s = ss + b * L;
    float acc = 0.f;
    #pragma unroll
    for (int dy = -1; dy <= 1; ++dy) {
        int yy = ly + dy;
        if ((unsigned)yy >= (unsigned)HH) continue;
        #pragma unroll
        for (int dx = -1; dx <= 1; ++dx) {
            int xx = lx + dx;
            if ((unsigned)xx >= (unsigned)WW) continue;
            int o = yy * WW + xx;
            acc += s[o] + s[BATCH * L + o] + s[2 * BATCH * L + o] + s[3 * BATCH * L + o];
        }
    }
    float n = sqrtf(acc);
    n = fmaxf(n, 1e-12f);
    rn[idx] = 1.0f / n;
}

// ---------------- transpose [C][pix] -> [pix][C] + bf16 hi/lo split (both images) ----
__global__ __launch_bounds__(256) void split_t(const float* __restrict__ lr,
                                               const float* __restrict__ refsr,
                                               __bf16* __restrict__ Qhi, __bf16* __restrict__ Qlo,
                                               __bf16* __restrict__ Khi, __bf16* __restrict__ Klo) {
    __shared__ float tile[64][65];
    int bz = blockIdx.z;
    int b = bz >> 1;
    const float* img = (bz & 1) ? refsr : lr;
    __bf16* dh = (bz & 1) ? Khi : Qhi;
    __bf16* dl = (bz & 1) ? Klo : Qlo;
    int u0 = blockIdx.x * 64, c0 = blockIdx.y * 64;
    int t = threadIdx.x;
    {
        int ul = t & 63, cl0 = t >> 6;
        const float* src = img + ((size_t)b * C3 + c0) * L + u0;
        #pragma unroll
        for (int r = 0; r < 16; ++r) {
            int cl = cl0 + r * 4;
            tile[cl][ul] = src[(size_t)cl * L + ul];
        }
    }
    __syncthreads();
    {
        int cl = t & 63, ul0 = t >> 6;
        __bf16* oh = dh + ((size_t)b * L + u0) * GK + c0 + cl;
        __bf16* ol = dl + ((size_t)b * L + u0) * GK + c0 + cl;
        #pragma unroll
        for (int r = 0; r < 16; ++r) {
            int ul = ul0 + r * 4;
            float v = tile[cl][ul];
            __bf16 h = (__bf16)v;
            float lo = v - (float)h;
            oh[(size_t)ul * GK] = h;
            ol[(size_t)ul * GK] = (__bf16)lo;
        }
    }
}

// ---------------- patch-major re-layout for the T1 fold gather source ----------------
// ref1 [b][c][192][192] -> ref1p [(b*64+c)*2304 + qy*48+qx][4][4]  (64B/patch, line-aligned)
__global__ __launch_bounds__(256) void t1prep(const float* __restrict__ ref, float* __restrict__ refp) {
    int id = blockIdx.x * 256 + threadIdx.x;     // 294912 patches
    int qx = id % 48, t = id / 48;
    int qy = t % 48, pc = t / 48;                // pc = b*64+c
    const float* src = ref + (size_t)pc * (192 * 192) + (qy * 4) * 192 + qx * 4;
    float* dst = refp + (size_t)id * 16;
    #pragma unroll
    for (int r = 0; r < 4; ++r) {
        f32x4 v = *(const f32x4*)(src + r * 192);
        *(f32x4*)(dst + r * 4) = v;
    }
}

// ---------------- split-bf16 MFMA GEMM NT over K=256: G[u,v] ----------------
__global__ __launch_bounds__(256) void gemm_g(const __bf16* __restrict__ Khi,
                                              const __bf16* __restrict__ Klo,
                                              const __bf16* __restrict__ Qhi,
                                              const __bf16* __restrict__ Qlo,
                                              float* __restrict__ Gg) {
    __shared__ __align__(16) __bf16 Ah[64 * BK2];
    __shared__ __align__(16) __bf16 Al[64 * BK2];
    __shared__ __align__(16) __bf16 Bh[128 * BK2];
    __shared__ __align__(16) __bf16 Bl[128 * BK2];
    int t = threadIdx.x;
    int lane = t & 63;
    int wv = t >> 6;
    int b = blockIdx.z;
    size_t ioff = (size_t)b * L * GK;
    const __bf16* Ahg = Khi + ioff;   // rows u (refsr)
    const __bf16* Alg = Klo + ioff;
    const __bf16* Bhg = Qhi + ioff;   // rows v (lr)
    const __bf16* Blg = Qlo + ioff;
    int m0 = blockIdx.x * 128;
    int l0 = blockIdx.y * 64;
    int wl = wv >> 1, wm = wv & 1;    // wave tile: 32(u) x 64(v)
    int q = lane >> 4, r16 = lane & 15;

    f32x4 acc[2][4];
    #pragma unroll
    for (int i = 0; i < 2; i++)
        #pragma unroll
        for (int j = 0; j < 4; j++) acc[i][j] = (f32x4)(0.f);

    for (int k0 = 0; k0 < GK; k0 += BK2) {
        #pragma unroll
        for (int hh = 0; hh < 2; ++hh) {          // A: 512 chunks of 16B
            int c = t + hh * 256;
            int row = c >> 3, qo = c & 7;
            size_t ga = (size_t)(l0 + row) * GK + k0 + ((qo ^ (row & 7)) * 8);
            gload16(Ahg + ga, &Ah[c * 8]);
            gload16(Alg + ga, &Al[c * 8]);
        }
        #pragma unroll
        for (int hh = 0; hh < 4; ++hh) {          // B: 1024 chunks
            int c = t + hh * 256;
            int row = c >> 3, qo = c & 7;
            size_t gb = (size_t)(m0 + row) * GK + k0 + ((qo ^ (row & 7)) * 8);
            gload16(Bhg + gb, &Bh[c * 8]);
            gload16(Blg + gb, &Bl[c * 8]);
        }
        __syncthreads();

        #pragma unroll
        for (int h = 0; h < 2; ++h) {             // two k-32 halves of BK=64
            bf16x8 ah[2], al[2], bh[4], bl[4];
            #pragma unroll
            for (int i = 0; i < 2; ++i) {
                int row = wl * 32 + i * 16 + r16;
                int ch = (h * 4 + q) ^ (row & 7);
                ah[i] = *(const bf16x8*)&Ah[row * BK2 + ch * 8];
                al[i] = *(const bf16x8*)&Al[row * BK2 + ch * 8];
            }
            #pragma unroll
            for (int j = 0; j < 4; ++j) {
                int row = wm * 64 + j * 16 + r16;
                int ch = (h * 4 + q) ^ (row & 7);
                bh[j] = *(const bf16x8*)&Bh[row * BK2 + ch * 8];
                bl[j] = *(const bf16x8*)&Bl[row * BK2 + ch * 8];
            }
            #pragma unroll
            for (int i = 0; i < 2; ++i)
                #pragma unroll
                for (int j = 0; j < 4; ++j) {
                    acc[i][j] = __builtin_amdgcn_mfma_f32_16x16x32_bf16(ah[i], bh[j], acc[i][j], 0, 0, 0);
                    acc[i][j] = __builtin_amdgcn_mfma_f32_16x16x32_bf16(ah[i], bl[j], acc[i][j], 0, 0, 0);
                    acc[i][j] = __builtin_amdgcn_mfma_f32_16x16x32_bf16(al[i], bh[j], acc[i][j], 0, 0, 0);
                }
        }
        __syncthreads();
    }

    float* Cb = Gg + (size_t)b * L * L;
    #pragma unroll
    for (int i = 0; i < 2; ++i) {
        int rowb = l0 + wl * 32 + i * 16 + q * 4;
        #pragma unroll
        for (int j = 0; j < 4; ++j) {
            int col = m0 + wm * 64 + j * 16 + r16;
            #pragma unroll
            for (int r = 0; r < 4; ++r)
                Cb[(size_t)(rowb + r) * L + col] = acc[i][j][r];
        }
    }
}

// ---------------- R[l,m] = rnK[l]*rnQ[m]*sum_{9 diag shifts} G[l+s, m+s] ----------------
__global__ __launch_bounds__(576) void stencil_R(const float* __restrict__ G,
                                                 const float* __restrict__ rnK,
                                                 const float* __restrict__ rnQ,
                                                 float* __restrict__ R) {
    int blk = blockIdx.x;                 // 0..1151
    int xcd = blk & 7, idx = blk >> 3;    // 144 chunks per XCD
    int gc = xcd * 144 + idx;             // contiguous l-chunks per XCD
    int b = gc / 576;
    int lbase = (gc % 576) * 4;
    int m0 = threadIdx.x * 4;
    const float* Gb = G + (size_t)b * L * L;
    int mdiv0 = m0 / 48, mmod0 = m0 % 48; // 4 cols never straddle a 48-boundary
    const float* rq = rnQ + b * L + m0;
    float rqv0 = rq[0], rqv1 = rq[1], rqv2 = rq[2], rqv3 = rq[3];

    #pragma unroll
    for (int li = 0; li < 4; ++li) {
        int l = lbase + li;
        int ly = l / 48, lx = l % 48;
        float a0 = 0.f, a1 = 0.f, a2 = 0.f, a3 = 0.f;
        #pragma unroll
        for (int dy = -1; dy <= 1; ++dy) {
            if ((unsigned)(ly + dy) >= 48u) continue;
            if ((unsigned)(mdiv0 + dy) >= 48u) continue;    // uniform over the 4 cols
            #pragma unroll
            for (int dx = -1; dx <= 1; ++dx) {
                if ((unsigned)(lx + dx) >= 48u) continue;
                int s = dy * 48 + dx;
                f32x4u v = *(const f32x4u*)(Gb + (size_t)(l + s) * L + s + m0);
                bool e0 = (unsigned)(mmod0 + dx) < 48u;     // only j=0,dx=-1 can fail
                bool e3 = (unsigned)(mmod0 + 3 + dx) < 48u; // only j=3,dx=+1 can fail
                a0 += e0 ? v[0] : 0.f;
                a1 += v[1];
                a2 += v[2];
                a3 += e3 ? v[3] : 0.f;
            }
        }
        float rk = rnK[b * L + l];
        f32x4 o = { a0 * rk * rqv0, a1 * rk * rqv1, a2 * rk * rqv2, a3 * rk * rqv3 };
        *(f32x4*)(R + (size_t)b * L * L + (size_t)l * L + m0) = o;  // cached: re-read by argmax/top3
    }
}

// ---------------- segmented argmax over l (ties -> lowest l) ----------------
__global__ void argmax_part(const float* __restrict__ R, float* __restrict__ pv, int* __restrict__ pi) {
    int m = blockIdx.x * 256 + threadIdx.x;
    int seg = blockIdx.y, b = blockIdx.z;
    const float* Rb = R + (size_t)b * L * L;
    float bv = -3.4e38f; int bi = 0;
    int l0 = seg * SEG;
    #pragma unroll 4
    for (int j = 0; j < SEG; j++) {
        float v = Rb[(size_t)(l0 + j) * L + m];
        if (v > bv) { bv = v; bi = l0 + j; }
    }
    int o = (b * NSEG + seg) * L + m;
    pv[o] = bv; pi[o] = bi;
}

__global__ void argmax_merge(const float* __restrict__ pv, const int* __restrict__ pi,
                             int* __restrict__ hidx) {
    int m = blockIdx.x * 256 + threadIdx.x;
    int b = blockIdx.y;
    float bv = -3.4e38f; int bi = 0;
    #pragma unroll
    for (int s = 0; s < NSEG; s++) {
        int o = (b * NSEG + s) * L + m;
        float v = pv[o];
        if (v > bv) { bv = v; bi = pi[o]; }
    }
    hidx[b * L + m] = bi;
}

// ---------------- segmented top-3 of s_l = R[hidx[l], m] ----------------
__global__ void top3_part(const float* __restrict__ R, const int* __restrict__ hidx,
                          float* __restrict__ pv, int* __restrict__ pr) {
    int m = blockIdx.x * 256 + threadIdx.x;
    int seg = blockIdx.y, b = blockIdx.z;
    const float* Rb = R + (size_t)b * L * L;
    __shared__ int hrow_s[SEG];
    if (threadIdx.x < SEG) hrow_s[threadIdx.x] = hidx[b * L + seg * SEG + threadIdx.x];
    __syncthreads();
    float v0 = -3.4e38f, v1 = -3.4e38f, v2 = -3.4e38f;
    int r0 = 0, r1 = 0, r2 = 0;
    #pragma unroll 4
    for (int j = 0; j < SEG; j++) {
        int row = hrow_s[j];
        float v = Rb[(size_t)row * L + m];
        if (v > v0)      { v2 = v1; r2 = r1; v1 = v0; r1 = r0; v0 = v; r0 = row; }
        else if (v > v1) { v2 = v1; r2 = r1; v1 = v;  r1 = row; }
        else if (v > v2) { v2 = v;  r2 = row; }
    }
    size_t o = ((size_t)(b * NSEG + seg) * 3) * L + m;
    pv[o] = v0; pv[o + L] = v1; pv[o + 2 * L] = v2;
    pr[o] = r0; pr[o + L] = r1; pr[o + 2 * L] = r2;
}

__global__ void top3_merge(const float* __restrict__ pv, const int* __restrict__ pr,
                           float* __restrict__ outS, int* __restrict__ effp) {
    int m = blockIdx.x * 256 + threadIdx.x;
    int b = blockIdx.y;
    float v0 = -3.4e38f, v1 = -3.4e38f, v2 = -3.4e38f;
    int r0 = 0, r1 = 0, r2 = 0;
    for (int s = 0; s < NSEG; s++) {
        size_t o = ((size_t)(b * NSEG + s) * 3) * L + m;
        #pragma unroll
        for (int j = 0; j < 3; j++) {
            float v = pv[o + (size_t)j * L];
            int r = pr[o + (size_t)j * L];
            if (v > v0)      { v2 = v1; r2 = r1; v1 = v0; r1 = r0; v0 = v; r0 = r; }
            else if (v > v1) { v2 = v1; r2 = r1; v1 = v;  r1 = r; }
            else if (v > v2) { v2 = v;  r2 = r; }
        }
    }
    outS[(0 * BATCH + b) * L + m] = v0;
    outS[(1 * BATCH + b) * L + m] = v1;
    outS[(2 * BATCH + b) * L + m] = v2;
    effp[(b * 3 + 0) * L + m] = ((r0 / 48) << 8) | (r0 % 48);
    effp[(b * 3 + 1) * L + m] = ((r1 / 48) << 8) | (r1 % 48);
    effp[(b * 3 + 2) * L + m] = ((r2 / 48) << 8) | (r2 % 48);
}

// ---------------- folds ----------------
// T1: thread = one 4x4 output quad; 9 x 64B line-aligned patch gathers (patch-major global).
__global__ __launch_bounds__(256) void fold_t1p(const float* __restrict__ refp, const int* __restrict__ effp,
                                                float* __restrict__ outT) {
    const int W = 192;
    int blk = blockIdx.x;                 // 3456 = 8 xcd * 9 tiles * 48 rr
    int xcd = blk & 7;
    int r = blk >> 3;
    int tile = r % 9;
    int rr = r / 9;                       // 0..47
    int i = rr % 3;
    int pw = rr / 3;                      // 0..15
    int plane = xcd + 8 * pw;             // 0..127
    int b = plane >> 6, c = plane & 63;
    int qid = tile * 256 + threadIdx.x;   // 0..2303
    int qy = qid / 48, qx = qid % 48;
    const int* e = effp + (b * 3 + i) * L;
    const float* src = refp + (size_t)plane * (2304 * 16);
    f32x4 acc0 = (f32x4)(0.f), acc1 = (f32x4)(0.f), acc2 = (f32x4)(0.f), acc3 = (f32x4)(0.f);
    #pragma unroll
    for (int dh = -1; dh <= 1; ++dh) {
        int ho = qy + dh;
        if ((unsigned)ho >= 48u) continue;
        #pragma unroll
        for (int dw = -1; dw <= 1; ++dw) {
            int wo = qx + dw;
            if ((unsigned)wo >= 48u) continue;
            int ep = e[ho * 48 + wo];
            int yq = (ep >> 8) - dh, xq = (ep & 255) - dw;
            if ((unsigned)yq >= 48u || (unsigned)xq >= 48u) continue;
            const float* P = src + (size_t)(yq * 48 + xq) * 16;
            acc0 += *(const f32x4*)(P);
            acc1 += *(const f32x4*)(P + 4);
            acc2 += *(const f32x4*)(P + 8);
            acc3 += *(const f32x4*)(P + 12);
        }
    }
    const float k = 1.0f / 9.0f;
    float* dst = outT + (((size_t)i * BATCH + b) * C1 + c) * (size_t)(W * W) + (qy * 4) * W + qx * 4;
    nts4(dst + 0 * W, acc0[0] * k, acc0[1] * k, acc0[2] * k, acc0[3] * k);
    nts4(dst + 1 * W, acc1[0] * k, acc1[1] * k, acc1[2] * k, acc1[3] * k);
    nts4(dst + 2 * W, acc2[0] * k, acc2[1] * k, acc2[2] * k, acc2[3] * k);
    nts4(dst + 3 * W, acc3[0] * k, acc3[1] * k, acc3[2] * k, acc3[3] * k);
}

// T2: LDS-staged. Block = one (plane, i). Stage the whole 96x96 plane from ref2
// into LDS in patch-major [quad][2][2] form (coalesced f32x4 reads + ds_write_b64
// rearrange), ep-table padded to stride 49. Gathers become ds_read_b128 on 32
// banks instead of 64-line L1 tag-walks. Also deletes the t2prep global round-trip.
__global__ __launch_bounds__(576) void fold_t2_lds(const float* __restrict__ ref, const int* __restrict__ effp,
                                                   float* __restrict__ outT) {
    const int W = 96;
    __shared__ float sP[2304 * 4];         // 36.9 KB patch-major plane
    __shared__ int   sE[48 * 49];          // 9.4 KB ep table, stride 49
    int blk = blockIdx.x;                  // 768 = 8 xcd * 96
    int xcd = blk & 7;
    int gc = xcd * 96 + (blk >> 3);        // contiguous chunks per XCD
    int plane = gc / 3, i = gc % 3;        // plane = b*128 + c
    int b = plane >> 7, c = plane & 127;
    int t = threadIdx.x;

    {   // stage plane: 4 coalesced f32x4 per thread -> patch-major ds_write_b64 pairs
        const float* src = ref + (size_t)plane * (W * W);
        #pragma unroll
        for (int k = 0; k < 4; ++k) {
            int id = t + k * 576;          // f32x4 chunk id over the plane
            int row = id / 24, x4 = id % 24;
            f32x4 v = *(const f32x4*)(src + row * W + x4 * 4);
            int qy = row >> 1, py = row & 1;
            int base0 = (qy * 48 + 2 * x4) * 4 + py * 2;
            f32x2 lo = { v[0], v[1] }, hi = { v[2], v[3] };
            *(f32x2*)&sP[base0] = lo;
            *(f32x2*)&sP[base0 + 4] = hi;
        }
        const int* e = effp + (b * 3 + i) * L;
        i32x4 ev = *(const i32x4*)(e + t * 4);
        #pragma unroll
        for (int k = 0; k < 4; ++k) {
            int id = t * 4 + k;
            sE[(id / 48) * 49 + (id % 48)] = ev[k];
        }
    }
    __syncthreads();

    int y = t / 12, x0q = (t % 12) * 4;    // 4 x-adjacent quads per thread
    f32x4 acc[4];
    #pragma unroll
    for (int xi = 0; xi < 4; ++xi) acc[xi] = (f32x4)(0.f);
    #pragma unroll
    for (int dh = -1; dh <= 1; ++dh) {
        int ho = y + dh;
        if ((unsigned)ho >= 48u) continue;
        int ep6[6];
        #pragma unroll
        for (int j = 0; j < 6; ++j) {
            int wo = x0q - 1 + j;
            ep6[j] = ((unsigned)wo < 48u) ? sE[ho * 49 + wo] : -1;
        }
        #pragma unroll
        for (int xi = 0; xi < 4; ++xi) {
            #pragma unroll
            for (int dw = -1; dw <= 1; ++dw) {
                int ep = ep6[xi + dw + 1];
                if (ep < 0) continue;
                int yq = (ep >> 8) - dh, xq = (ep & 255) - dw;
                if ((unsigned)yq >= 48u || (unsigned)xq >= 48u) continue;
                acc[xi] += *(const f32x4*)&sP[(yq * 48 + xq) * 4];
            }
        }
    }
    const float k = 1.0f / 9.0f;
    float* dst = outT + (((size_t)i * BATCH + b) * C2 + c) * (size_t)(W * W) + (2 * y) * W + x0q * 2;
    nts4(dst,         acc[0][0] * k, acc[0][1] * k, acc[1][0] * k, acc[1][1] * k);
    nts4(dst + 4,     acc[2][0] * k, acc[2][1] * k, acc[3][0] * k, acc[3][1] * k);
    nts4(dst + W,     acc[0][2] * k, acc[0][3] * k, acc[1][2] * k, acc[1][3] * k);
    nts4(dst + W + 4, acc[2][2] * k, acc[2][3] * k, acc[3][2] * k, acc[3][3] * k);
}

// T3: LDS-staged gather (proven R4).
__global__ __launch_bounds__(576) void fold_t3_lds(const float* __restrict__ ref, const int* __restrict__ effp,
                                                   float* __restrict__ outT) {
    const int W = 48;
    __shared__ float sP[2304];
    __shared__ int   sE[48 * 49];          // stride 49: rotates banks per row
    int blk = blockIdx.x;                  // 1536 = 8 xcd * 192
    int xcd = blk & 7;
    int gc = xcd * 192 + (blk >> 3);       // contiguous plane-chunks per XCD
    int plane = gc / 3, i = gc % 3;        // plane = b*256 + c
    int b = plane >> 8, c = plane & 255;
    int t = threadIdx.x;

    {   // stage plane (one float4/thread) + ep table (one int4/thread, re-padded)
        const float* src = ref + (size_t)plane * (W * W);
        *(f32x4*)&sP[t * 4] = *(const f32x4*)(src + t * 4);
        const int* e = effp + (b * 3 + i) * L;
        i32x4 ev = *(const i32x4*)(e + t * 4);
        #pragma unroll
        for (int k = 0; k < 4; ++k) {
            int id = t * 4 + k;
            sE[(id / 48) * 49 + (id % 48)] = ev[k];
        }
    }
    __syncthreads();

    int y = t / 12, x0 = (t % 12) * 4;     // 576 threads cover 48x12 quads of 4 px
    float s0 = 0.f, s1 = 0.f, s2 = 0.f, s3 = 0.f;
    #pragma unroll
    for (int dh = -1; dh <= 1; ++dh) {
        int ho = y + dh;
        if ((unsigned)ho >= 48u) continue;
        int ep6[6];
        #pragma unroll
        for (int j = 0; j < 6; ++j) {
            int wo = x0 - 1 + j;
            ep6[j] = ((unsigned)wo < 48u) ? sE[ho * 49 + wo] : -1;
        }
        #pragma unroll
        for (int xi = 0; xi < 4; ++xi) {
            float acc = 0.f;
            #pragma unroll
            for (int dw = -1; dw <= 1; ++dw) {
                int ep = ep6[xi + dw + 1];
                if (ep < 0) continue;
                int yy = (ep >> 8) - dh, xx = (ep & 255) - dw;
                if ((unsigned)yy >= 48u || (unsigned)xx >= 48u) continue;
                acc += sP[yy * W + xx];
            }
            if (xi == 0) s0 += acc; else if (xi == 1) s1 += acc;
            else if (xi == 2) s2 += acc; else s3 += acc;
        }
    }
    const float k = 1.0f / 9.0f;
    nts4(outT + (((size_t)i * BATCH + b) * C3 + c) * (size_t)(W * W) + y * W + x0,
         s0 * k, s1 * k, s2 * k, s3 * k);
}

extern "C" void kernel_launch(void* const* d_in, const int* in_sizes, int n_in,
                              void* d_out, int out_size, void* d_ws, size_t ws_size,
                              hipStream_t stream) {
    const float* lr    = (const float*)d_in[0];
    const float* refsr = (const float*)d_in[1];
    const float* ref1  = (const float*)d_in[2];
    const float* ref2  = (const float*)d_in[3];
    const float* ref3  = (const float*)d_in[4];
    float* out = (float*)d_out;

    float*  R   = (float*)d_ws;                              // B*L*L fp32
    float*  G   = R + (size_t)BATCH * L * L;                 // B*L*L fp32
    __bf16* Khi = (__bf16*)(G + (size_t)BATCH * L * L);      // B*L*GK bf16 each
    __bf16* Klo = Khi + (size_t)BATCH * L * GK;
    __bf16* Qhi = Klo + (size_t)BATCH * L * GK;
    __bf16* Qlo = Qhi + (size_t)BATCH * L * GK;
    float* ssQ4 = (float*)(Qlo + (size_t)BATCH * L * GK);    // 4 * B*L
    float* ssK4 = ssQ4 + 4 * BATCH * L;
    float* rnQ = ssK4 + 4 * BATCH * L;
    float* rnK = rnQ + BATCH * L;
    float* apv = rnK + BATCH * L;
    float* pv  = apv + BATCH * NSEG * L;
    int*   api = (int*)(pv + (size_t)BATCH * NSEG * 3 * L);
    int*   pr  = api + BATCH * NSEG * L;
    int*   hidx = pr + (size_t)BATCH * NSEG * 3 * L;
    int*   effp = hidx + BATCH * L;
    float* ref1p = (float*)(effp + BATCH * 3 * L);           // 2*64*2304*16 fp32 (18.9 MB)

    ssq_kernel<<<dim3(18, 8), 256, 0, stream>>>(lr, refsr, ssQ4, ssK4);
    norm_kernel<<<dim3(18, 2), 256, 0, stream>>>(ssQ4, ssK4, rnQ, rnK);
    split_t<<<dim3(36, 4, BATCH * 2), 256, 0, stream>>>(lr, refsr, Qhi, Qlo, Khi, Klo);
    t1prep<<<1152, 256, 0, stream>>>(ref1, ref1p);

    gemm_g<<<dim3(18, 36, BATCH), 256, 0, stream>>>(Khi, Klo, Qhi, Qlo, G);
    stencil_R<<<1152, 576, 0, stream>>>(G, rnK, rnQ, R);

    argmax_part<<<dim3(9, NSEG, BATCH), 256, 0, stream>>>(R, apv, api);
    argmax_merge<<<dim3(9, BATCH), 256, 0, stream>>>(apv, api, hidx);
    top3_part<<<dim3(9, NSEG, BATCH), 256, 0, stream>>>(R, hidx, pv, pr);
    top3_merge<<<dim3(9, BATCH), 256, 0, stream>>>(pv, pr, out, effp);

    fold_t3_lds<<<1536, 576, 0, stream>>>(ref3, effp, out + OFF_T3);
    fold_t2_lds<<<768,  576, 0, stream>>>(ref2, effp, out + OFF_T2);
    fold_t1p<<<3456, 256, 0, stream>>>(ref1p, effp, out + OFF_T1);
}